// Round 7
// baseline (369.229 us; speedup 1.0000x reference)
//
#include <hip/hip_runtime.h>

typedef __bf16 bf16_t;
typedef bf16_t bf16x8 __attribute__((ext_vector_type(8)));
typedef bf16_t bf16x4 __attribute__((ext_vector_type(4)));
typedef float f32x4 __attribute__((ext_vector_type(4)));
typedef unsigned u32x4 __attribute__((ext_vector_type(4)));

// async global->LDS 16B per lane. LDS dest = wave-uniform base + lane*16
// (m97/m104): per-lane pointers must be linear in lane index.
__device__ __forceinline__ void async_copy16(const void* g, void* l) {
  __builtin_amdgcn_global_load_lds(
      (const __attribute__((address_space(1))) unsigned int*)(unsigned long long)g,
      (__attribute__((address_space(3))) unsigned int*)(unsigned int)(unsigned long long)l,
      16, 0, 0);
}

// guaranteed single-instruction exp2 / rcp
__device__ __forceinline__ float fast_exp2(float x) {
#if __has_builtin(__builtin_amdgcn_exp2f)
  return __builtin_amdgcn_exp2f(x);
#else
  float r;
  asm volatile("v_exp_f32 %0, %1\n\ts_nop 0" : "=v"(r) : "v"(x));
  return r;
#endif
}
__device__ __forceinline__ float fast_rcp(float x) {
#if __has_builtin(__builtin_amdgcn_rcpf)
  return __builtin_amdgcn_rcpf(x);
#else
  float r;
  asm volatile("v_rcp_f32 %0, %1\n\ts_nop 0" : "=v"(r) : "v"(x));
  return r;
#endif
}

__device__ __forceinline__ unsigned pack_bf16(float x, float y) {
  bf16_t lo = (bf16_t)x, hi = (bf16_t)y;
  unsigned short ul, uh;
  __builtin_memcpy(&ul, &lo, 2);
  __builtin_memcpy(&uh, &hi, 2);
  return (unsigned)ul | ((unsigned)uh << 16);
}

// Q-projection carries 1/8 (softmax scale) * log2e (exp->exp2 conversion)
#define QSCALE 0.180336688f

// ---------------- merged prep: 10 weight transposes + x/h/W1 bf16 cast ------
struct SrcPtrs { const float* p[10]; };
__global__ __launch_bounds__(256) void prep_main(
    SrcPtrs srcs, bf16_t* __restrict__ dstbase,
    const float* __restrict__ a, const float* __restrict__ b,
    const float* __restrict__ w1, bf16_t* __restrict__ dst1,
    bf16_t* __restrict__ dstw) {
  __shared__ float tile[32][33];
  int bid = blockIdx.x;
  int tid = threadIdx.x;
  if (bid < 10240) {
    int z = bid >> 10;
    int rem = bid & 1023;
    const float* src = srcs.p[z];
    bf16_t* dst = dstbase + (size_t)z * 1048576;
    float scale = (z == 0) ? QSCALE : ((z == 4) ? 0.03125f : 1.f);
    int bx = (rem & 31) * 32;   // n base
    int by = (rem >> 5) * 32;   // k base
    int tx = tid & 31, ty = tid >> 5;  // 32x8
#pragma unroll
    for (int i = 0; i < 32; i += 8)
      tile[ty + i][tx] = src[(size_t)(by + ty + i) * 1024 + bx + tx];
    __syncthreads();
#pragma unroll
    for (int i = 0; i < 32; i += 8)
      dst[(size_t)(bx + ty + i) * 1024 + by + tx] = (bf16_t)(tile[tx][ty + i] * scale);
  } else {
    int i = ((bid - 10240) * 256 + tid) * 8;  // [0, 9M)
    const float* s;
    bf16_t* d;
    if (i < 4194304) { s = a + i; d = dst1 + i; }
    else if (i < 8388608) { s = b + i - 4194304; d = dst1 + i; }
    else { s = w1 + i - 8388608; d = dstw + (i - 8388608); }
    float4 u = *(const float4*)s;
    float4 v = *(const float4*)(s + 4);
    bf16x8 o;
    o[0]=(bf16_t)u.x; o[1]=(bf16_t)u.y; o[2]=(bf16_t)u.z; o[3]=(bf16_t)u.w;
    o[4]=(bf16_t)v.x; o[5]=(bf16_t)v.y; o[6]=(bf16_t)v.z; o[7]=(bf16_t)v.w;
    *(bf16x8*)d = o;
  }
}

// --- bias concat [q|k|v|ck|cv|cq|zeros] x1024 + fused FFN bias (blk 28-31) --
__global__ __launch_bounds__(256) void prep_bias_kernel(
    const float* __restrict__ bq, const float* __restrict__ bk,
    const float* __restrict__ bv, const float* __restrict__ bck,
    const float* __restrict__ bcv, const float* __restrict__ bcq,
    const bf16_t* __restrict__ wt9, const float* __restrict__ b1,
    const float* __restrict__ b2, float* __restrict__ cb,
    float* __restrict__ cb2) {
  int bid = blockIdx.x;
  if (bid < 28) {
    int i = bid * 256 + threadIdx.x;
    if (i < 1024) cb[i] = bq[i] * QSCALE;
    else if (i < 2048) cb[i] = bk[i - 1024];
    else if (i < 3072) cb[i] = bv[i - 2048];
    else if (i < 4096) cb[i] = bck[i - 3072];
    else if (i < 5120) cb[i] = bcv[i - 4096];
    else if (i < 6144) cb[i] = bcq[i - 5120] * 0.03125f;
    else cb[i] = 0.f;  // zeros for the P-GEMM bias
  } else {
    // cb2[n] = sum_h b1[h]*W2[h][n] + b2[n];  wt9[n][h] = W2[h][n]
    int n = (bid - 28) * 256 + threadIdx.x;
    const bf16_t* row = wt9 + (size_t)n * 1024;
    float acc = 0.f;
#pragma unroll 4
    for (int h = 0; h < 1024; h += 8) {
      bf16x8 v = *(const bf16x8*)(row + h);
      float4 ba = *(const float4*)(b1 + h);
      float4 bb = *(const float4*)(b1 + h + 4);
      acc += ba.x*(float)v[0] + ba.y*(float)v[1] + ba.z*(float)v[2] + ba.w*(float)v[3]
           + bb.x*(float)v[4] + bb.y*(float)v[5] + bb.z*(float)v[6] + bb.w*(float)v[7];
    }
    cb2[n] = acc + b2[n];
  }
}

// ---------------- shared GEMM core: C[*,ldC] = A[*,1024] @ Bt[*,1024]^T -----
template <int BN, int MI, bool HAS_RES, bool TRANS_OUT, bool DBUF>
__device__ __forceinline__ void gemm_core(
    const bf16_t* __restrict__ A, const bf16_t* __restrict__ Bt,
    const float* __restrict__ bias, const bf16_t* __restrict__ res,
    bf16_t* __restrict__ C, int ldC, int bm, int bn,
    bf16_t* As, bf16_t* Bs) {
  constexpr int NI = 4;
  constexpr int ASZ = 128 * 64, BSZ = BN * 64;
  int tid = threadIdx.x;
  int w = tid >> 6, lane = tid & 63;
  int fm = lane & 15, fq = lane >> 4;
  int wm = (BN == 128) ? (w >> 1) * 64 : w * 32;
  int wn = (BN == 128) ? (w & 1) * 64 : 0;
  f32x4 acc[MI][NI] = {};

  auto stage = [&](int kt, int half) {
    bf16_t* Ad = DBUF ? As + half * ASZ : As;
    bf16_t* Bd = DBUF ? Bs + half * BSZ : Bs;
#pragma unroll
    for (int i = 0; i < 4; i++) {  // A: 128 rows x 8 chunks
      int c = i * 256 + tid;
      int row = c >> 3, skg = (c & 7) ^ (row & 7);
      async_copy16(A + (size_t)(bm + row) * 1024 + kt + skg * 8, &Ad[c * 8]);
    }
#pragma unroll
    for (int i = 0; i < BN / 32; i++) {  // B: BN rows x 8 chunks
      int c = i * 256 + tid;
      int row = c >> 3, skg = (c & 7) ^ (row & 7);
      async_copy16(Bt + (size_t)(bn + row) * 1024 + kt + skg * 8, &Bd[c * 8]);
    }
  };
  auto compute = [&](int half) {
    const bf16_t* Ac = DBUF ? As + half * ASZ : As;
    const bf16_t* Bc = DBUF ? Bs + half * BSZ : Bs;
#pragma unroll
    for (int ks = 0; ks < 2; ks++) {
      bf16x8 af[MI], bfr[NI];
      int kg = ks * 4 + fq;
#pragma unroll
      for (int mi = 0; mi < MI; mi++) {
        int row = wm + mi * 16 + fm;
        af[mi] = *(const bf16x8*)&Ac[row * 64 + ((kg ^ (row & 7)) * 8)];
      }
#pragma unroll
      for (int ni = 0; ni < NI; ni++) {
        int row = wn + ni * 16 + fm;
        bfr[ni] = *(const bf16x8*)&Bc[row * 64 + ((kg ^ (row & 7)) * 8)];
      }
#pragma unroll
      for (int mi = 0; mi < MI; mi++)
#pragma unroll
        for (int ni = 0; ni < NI; ni++)
          acc[mi][ni] = __builtin_amdgcn_mfma_f32_16x16x32_bf16(
              af[mi], bfr[ni], acc[mi][ni], 0, 0, 0);
    }
  };

  if (DBUF) {
    stage(0, 0);
    __syncthreads();  // tile 0 resident
#pragma unroll
    for (int t = 0; t < 16; t++) {
      if (t < 15) stage((t + 1) * 64, (t + 1) & 1);  // prefetch next half
      compute(t & 1);
      __syncthreads();  // drains vmcnt(0) AFTER compute; frees half t&1
    }
  } else {
    for (int kt = 0; kt < 1024; kt += 64) {
      stage(kt, 0);
      __syncthreads();  // drains vmcnt(0): copies visible
      compute(0);
      __syncthreads();  // protect LDS reuse
    }
  }

#pragma unroll
  for (int mi = 0; mi < MI; mi++) {
#pragma unroll
    for (int ni = 0; ni < NI; ni++) {
      int col = bn + wn + ni * 16 + fm;
      float bv = bias[col];
      if (TRANS_OUT) {
        int rowb = bm + wm + mi * 16 + fq * 4;
        bf16x4 w4;
#pragma unroll
        for (int r = 0; r < 4; r++) w4[r] = (bf16_t)(acc[mi][ni][r] + bv);
        *(bf16x4*)&C[(size_t)col * ldC + rowb] = w4;  // C^T: ldC = M
      } else {
#pragma unroll
        for (int r = 0; r < 4; r++) {
          int row = bm + wm + mi * 16 + fq * 4 + r;  // C/D map (m89/m91)
          float v = acc[mi][ni][r] + bv;
          if (HAS_RES) v += (float)res[(size_t)row * ldC + col];
          C[(size_t)row * ldC + col] = (bf16_t)v;
        }
      }
    }
  }
}

// XCD swizzle: hw assigns blocks round-robin by linear id (xcd = lin&7 when
// count%8==0). Remap to 4 bm-groups x 2 bn-groups: per-XCD working set
// (A-slice + B-slice) ~3MB fits the 4MiB L2.
template <int GX, int GY, int BN>
__device__ __forceinline__ void xcd_map(int lin, int& bm, int& bn) {
  constexpr int HX = GX / 2, QY = GY / 4;
  int xcd = lin & 7, idx = lin >> 3;
  int ly = idx / HX, lx = idx - ly * HX;
  bm = ((xcd >> 1) * QY + ly) * 128;
  bn = ((xcd & 1) * HX + lx) * BN;
}

// ---------------- standalone GEMM kernel (BN=64, grid (16,32) swizzled) -----
// Grid = 512 blocks = 2/CU (grid-limited) -> DBUF 2-phase core.
template <bool HAS_RES, bool TRANS_OUT>
__global__ __launch_bounds__(256) void gemm_bf16(
    const bf16_t* __restrict__ A, const bf16_t* __restrict__ Bt,
    const float* __restrict__ bias, const bf16_t* __restrict__ res,
    bf16_t* __restrict__ C, int ldC) {
  __shared__ bf16_t As[2 * 128 * 64];  // 32 KB
  __shared__ bf16_t Bs[2 * 64 * 64];   // 16 KB
  int bm, bn;
  xcd_map<16, 32, 64>(blockIdx.x + 16 * blockIdx.y, bm, bn);
  gemm_core<64, 2, HAS_RES, TRANS_OUT, true>(A, Bt, bias, res, C, ldC, bm, bn, As, Bs);
}

// ======== MEGA-GEMM: all MFMA work that depends only on prep, ONE launch ====
// R5/R6 lesson: fusing staged GEMM with VALU-bound attn captures ~0 overlap
// (shared VALU issue + barrier drains + L2 thrash). Instead pack all the
// INDEPENDENT MFMA work together so tails fill with more MFMA blocks:
//   [0,768):     qkv C[4096][3072] = xb @ [Wq|Wk|Wv]   (128x128, swizzled)
//   [768,896):   Pt[1024][1024]    = wt9 @ w1bf^T      (128x64)
//   [896,1408):  kbuf[4096][1024]  = hb @ Wck          (128x64, swizzled)
//   [1408,1920): vt[1024][4096]    = (hb @ Wcv)^T      (128x64, swizzled)
// All segment bases are 0 mod 8 -> per-segment xcd = bid&7 stays valid.
// 1920 blocks, 32KB LDS -> 5/CU cap, ~7.5/CU queued: good balance, no tail.
__global__ __launch_bounds__(256) void gemm_mega(
    const bf16_t* __restrict__ xb, const bf16_t* __restrict__ wt0,
    const bf16_t* __restrict__ wt9, const bf16_t* __restrict__ w1bf,
    const bf16_t* __restrict__ hb, const bf16_t* __restrict__ wt4,
    const float* __restrict__ cb, bf16_t* __restrict__ qkv,
    bf16_t* __restrict__ pt, bf16_t* __restrict__ kbuf,
    bf16_t* __restrict__ vt) {
  __shared__ bf16_t smem[2 * 128 * 64];  // 32 KB
  int bid = blockIdx.x;
  if (bid < 768) {            // qkv: 128x128 tiles
    int bm, bn;
    xcd_map<24, 32, 128>(bid, bm, bn);
    gemm_core<128, 4, false, false, false>(xb, wt0, cb, nullptr, qkv, 3072,
                                           bm, bn, smem, smem + 128 * 64);
  } else if (bid < 896) {     // P-GEMM: Pt = wt9 @ w1bf^T
    int idx = bid - 768;
    gemm_core<64, 2, false, false, false>(wt9, w1bf, cb + 6144, nullptr, pt, 1024,
                                          (idx >> 4) * 128, (idx & 15) * 64,
                                          smem, smem + 128 * 64);
  } else if (bid < 1408) {    // K-proj: kbuf = hb @ Wck
    int bm, bn;
    xcd_map<16, 32, 64>(bid - 896, bm, bn);
    gemm_core<64, 2, false, false, false>(hb, wt4 + 1048576, cb + 3072, nullptr,
                                          kbuf, 1024, bm, bn, smem, smem + 128 * 64);
  } else {                    // V-proj: vt = (hb @ Wcv)^T
    int bm, bn;
    xcd_map<16, 32, 64>(bid - 1408, bm, bn);
    gemm_core<64, 2, false, true, false>(hb, wt4 + 2097152, cb + 4096, nullptr,
                                         vt, 4096, bm, bn, smem, smem + 128 * 64);
  }
}

// ---------------- self-attn core: causal softmax over C=64 channels ---------
// QKV packed [4096][3072] bf16 (Q|K|V), O [4096][1024] bf16.
// Q pre-scaled (1/8)*log2e in the projection.
// ZERO-LDS scalar-path form (R4-verified ~48us = VALU/TRANS issue floor):
// K/V rows are wave-uniform -> s_load to SGPRs; bf16 unpack on SALU; one
// shared mask cmp per pair; even-lane diagonal added once after the loop.
__global__ __launch_bounds__(256) void self_attn_kernel(
    const bf16_t* __restrict__ QKV, bf16_t* __restrict__ O) {
  int tid = threadIdx.x;
  int lane = tid & 63;
  int unit = __builtin_amdgcn_readfirstlane(blockIdx.x * 4 + (tid >> 6));
  int m = unit >> 4, h = unit & 15;
  size_t base = (size_t)m * 3072 + h * 64;
  size_t iq = base + lane;
  float qv = (float)QKV[iq];                 // (1/8)*log2e pre-folded
  float kown = (float)QKV[iq + 1024];        // K[lane] (diagonal term)
  float vown = (float)QKV[iq + 2048];        // V[lane]
  const u32x4* Krow = (const u32x4*)(QKV + base + 1024);
  const u32x4* Vrow = (const u32x4*)(QKV + base + 2048);
  u32x4 K4[8], V4[8];
#pragma unroll
  for (int i = 0; i < 8; i++) { K4[i] = Krow[i]; V4[i] = Vrow[i]; }
  float l0 = 0.f, l1 = 0.f, o0 = 0.f, o1 = 0.f;
#pragma unroll
  for (int p = 0; p < 32; p++) {
    unsigned kw = K4[p >> 2][p & 3];   // scalar: (k_{2p}, k_{2p+1}) bf16 pair
    unsigned vw = V4[p >> 2][p & 3];
    float k0 = __uint_as_float(kw << 16);          // SALU
    float k1 = __uint_as_float(kw & 0xffff0000u);  // SALU
    float v0 = __uint_as_float(vw << 16);
    float v1 = __uint_as_float(vw & 0xffff0000u);
    float e0 = fast_exp2(qv * k0);
    float e1 = fast_exp2(qv * k1);
    bool c = lane >= 2 * p + 1;        // ONE cmp; excludes even-lane diagonal
    e0 = c ? e0 : 0.f;
    e1 = c ? e1 : 0.f;
    l0 += e0; o0 = fmaf(e0, v0, o0);
    l1 += e1; o1 = fmaf(e1, v1, o1);
  }
  // even-lane diagonal (k == lane, excluded by the strict shared mask)
  float ed = fast_exp2(qv * kown);
  ed = ((lane & 1) == 0) ? ed : 0.f;
  float l = (l0 + l1) + ed;
  float o = fmaf(ed, vown, o0 + o1);
  O[(size_t)m * 1024 + h * 64 + lane] = (bf16_t)(o * fast_rcp(l));
}

// ---------------- cross-attn, MFMA flash ------------------------------------
__global__ __launch_bounds__(256) void cross_attn_mfma(
    const bf16_t* __restrict__ Q, const bf16_t* __restrict__ Kb,
    const bf16_t* __restrict__ Vt, bf16_t* __restrict__ O) {
  __shared__ bf16_t Ks[64 * 64];
  __shared__ bf16_t Vs[64 * 64];
  int tid = threadIdx.x;
  int w = tid >> 6, lane = tid & 63;
  int fm = lane & 15, fq = lane >> 4;
  int bh = blockIdx.x;
  int b = bh >> 4, h = bh & 15;
  int q0 = blockIdx.y * 64 + w * 16;
  const bf16_t* Qp = Q + (size_t)(b * 512 + q0 + fm) * 1024 + h * 64 + fq * 8;
  bf16x8 qf0 = *(const bf16x8*)Qp;
  bf16x8 qf1 = *(const bf16x8*)(Qp + 32);
  f32x4 o[4] = {};  // O^T tiles ct: lane holds O^T[c=ct*16+fq*4+r][q=fm]
  float mx = -1e30f, l = 0.f;
  for (int k0 = 0; k0 < 512; k0 += 64) {
    __syncthreads();  // previous tile's LDS reads complete
#pragma unroll
    for (int i = 0; i < 2; i++) {  // 64 rows x 8 chunks, XOR swizzle
      int c = i * 256 + tid;
      int row = c >> 3, kg = (c & 7) ^ (row & 7);
      async_copy16(Kb + (size_t)(b * 512 + k0 + row) * 1024 + h * 64 + kg * 8,
                   &Ks[c * 8]);
      async_copy16(Vt + (size_t)(h * 64 + row) * 4096 + b * 512 + k0 + kg * 8,
                   &Vs[c * 8]);
    }
    __syncthreads();  // drain global_load_lds
    // S^T tiles mt: lane holds S^T[k=mt*16+fq*4+r][q=fm]
    f32x4 s[4] = {};
#pragma unroll
    for (int mt = 0; mt < 4; mt++) {
      int row = mt * 16 + fm;
#pragma unroll
      for (int f = 0; f < 2; f++) {
        int kg = f * 4 + fq;
        bf16x8 kf = *(const bf16x8*)&Ks[row * 64 + ((kg ^ (row & 7)) * 8)];
        s[mt] = __builtin_amdgcn_mfma_f32_16x16x32_bf16(
            kf, (f ? qf1 : qf0), s[mt], 0, 0, 0);
      }
    }
    // online softmax (stats per q=fm, replicated across quads)
    float smax = -1e30f;
#pragma unroll
    for (int mt = 0; mt < 4; mt++)
#pragma unroll
      for (int r = 0; r < 4; r++) smax = fmaxf(smax, s[mt][r]);
    smax = fmaxf(smax, __shfl_xor(smax, 16, 64));
    smax = fmaxf(smax, __shfl_xor(smax, 32, 64));
    float nm = fmaxf(mx, smax);
    float corr = __expf(mx - nm);
    float ladd = 0.f;
    unsigned pk0[4], pk1[4];
#pragma unroll
    for (int mt = 0; mt < 4; mt++) {
      float p0 = __expf(s[mt][0] - nm);
      float p1 = __expf(s[mt][1] - nm);
      float p2 = __expf(s[mt][2] - nm);
      float p3 = __expf(s[mt][3] - nm);
      ladd += (p0 + p1) + (p2 + p3);
      pk0[mt] = pack_bf16(p0, p1);
      pk1[mt] = pack_bf16(p2, p3);
    }
    ladd += __shfl_xor(ladd, 16, 64);
    ladd += __shfl_xor(ladd, 32, 64);
    l = l * corr + ladd;
#pragma unroll
    for (int ct = 0; ct < 4; ct++)
#pragma unroll
      for (int r = 0; r < 4; r++) o[ct][r] *= corr;
    union U { unsigned u[4]; bf16x8 v; } pf[2];
    int sl0 = ((fq & 1) * 2) * 16 + fm;
    int sl1 = sl0 + 16;
    bool hi = fq >= 2;
#pragma unroll
    for (int f = 0; f < 2; f++) {
      unsigned a0 = (unsigned)__shfl((int)pk0[f * 2],     sl0, 64);
      unsigned b0 = (unsigned)__shfl((int)pk0[f * 2 + 1], sl0, 64);
      unsigned a1 = (unsigned)__shfl((int)pk1[f * 2],     sl0, 64);
      unsigned b1 = (unsigned)__shfl((int)pk1[f * 2 + 1], sl0, 64);
      unsigned a2 = (unsigned)__shfl((int)pk0[f * 2],     sl1, 64);
      unsigned b2 = (unsigned)__shfl((int)pk0[f * 2 + 1], sl1, 64);
      unsigned a3 = (unsigned)__shfl((int)pk1[f * 2],     sl1, 64);
      unsigned b3 = (unsigned)__shfl((int)pk1[f * 2 + 1], sl1, 64);
      pf[f].u[0] = hi ? b0 : a0;
      pf[f].u[1] = hi ? b1 : a1;
      pf[f].u[2] = hi ? b2 : a2;
      pf[f].u[3] = hi ? b3 : a3;
    }
#pragma unroll
    for (int ct = 0; ct < 4; ct++) {
      int row = ct * 16 + fm;
#pragma unroll
      for (int f = 0; f < 2; f++) {
        int kg = f * 4 + fq;
        bf16x8 vf = *(const bf16x8*)&Vs[row * 64 + ((kg ^ (row & 7)) * 8)];
        o[ct] = __builtin_amdgcn_mfma_f32_16x16x32_bf16(vf, pf[f].v, o[ct], 0, 0, 0);
      }
    }
    mx = nm;
  }
  float inv = 1.f / l;
  bf16_t* Op = O + (size_t)(b * 512 + q0 + fm) * 1024 + h * 64 + fq * 4;
#pragma unroll
  for (int ct = 0; ct < 4; ct++) {
    bf16x4 w4;
    w4[0] = (bf16_t)(o[ct][0] * inv);
    w4[1] = (bf16_t)(o[ct][1] * inv);
    w4[2] = (bf16_t)(o[ct][2] * inv);
    w4[3] = (bf16_t)(o[ct][3] * inv);
    *(bf16x4*)(Op + ct * 16) = w4;
  }
}

// ---------------- LayerNorm D=1024, bf16 in, OutT out -----------------------
template <typename OutT>
__global__ __launch_bounds__(256) void ln_kernel(
    const bf16_t* __restrict__ X, const float* __restrict__ gamma,
    const float* __restrict__ beta, OutT* __restrict__ Y) {
  __shared__ float red[8];
  int row = blockIdx.x;
  int tid = threadIdx.x;
  bf16x4 x4 = *(const bf16x4*)(X + (size_t)row * 1024 + tid * 4);
  float4 v = {(float)x4[0], (float)x4[1], (float)x4[2], (float)x4[3]};
  float s = (v.x + v.y) + (v.z + v.w);
  float ss = fmaf(v.x, v.x, fmaf(v.y, v.y, fmaf(v.z, v.z, v.w * v.w)));
#pragma unroll
  for (int off = 32; off > 0; off >>= 1) {
    s  += __shfl_down(s, off, 64);
    ss += __shfl_down(ss, off, 64);
  }
  if ((tid & 63) == 0) { red[tid >> 6] = s; red[4 + (tid >> 6)] = ss; }
  __syncthreads();
  float S  = (red[0] + red[1]) + (red[2] + red[3]);
  float SS = (red[4] + red[5]) + (red[6] + red[7]);
  float mu = S * (1.f / 1024.f);
  float var = SS * (1.f / 1024.f) - mu * mu;
  float inv = rsqrtf(var + 1e-5f);
  float4 g = *(const float4*)(gamma + tid * 4);
  float4 b = *(const float4*)(beta + tid * 4);
  float r0 = (v.x - mu) * inv * g.x + b.x;
  float r1 = (v.y - mu) * inv * g.y + b.y;
  float r2 = (v.z - mu) * inv * g.z + b.z;
  float r3 = (v.w - mu) * inv * g.w + b.w;
  OutT* yp = Y + (size_t)row * 1024 + tid * 4;
  yp[0] = (OutT)r0; yp[1] = (OutT)r1; yp[2] = (OutT)r2; yp[3] = (OutT)r3;
}

extern "C" void kernel_launch(void* const* d_in, const int* in_sizes, int n_in,
                              void* d_out, int out_size, void* d_ws, size_t ws_size,
                              hipStream_t stream) {
  (void)in_sizes; (void)n_in; (void)out_size; (void)ws_size;
  const float* x  = (const float*)d_in[0];
  const float* hh = (const float*)d_in[1];
  SrcPtrs sp;
  sp.p[0] = (const float*)d_in[2];  sp.p[1] = (const float*)d_in[4];
  sp.p[2] = (const float*)d_in[6];  sp.p[3] = (const float*)d_in[8];
  sp.p[4] = (const float*)d_in[10]; sp.p[5] = (const float*)d_in[12];
  sp.p[6] = (const float*)d_in[14]; sp.p[7] = (const float*)d_in[16];
  sp.p[8] = (const float*)d_in[20]; sp.p[9] = (const float*)d_in[22];
  const float* W1f = (const float*)d_in[20];
  const float* bq  = (const float*)d_in[3];
  const float* bk  = (const float*)d_in[5];
  const float* bv  = (const float*)d_in[7];
  const float* bo  = (const float*)d_in[9];
  const float* bck = (const float*)d_in[13];
  const float* bcv = (const float*)d_in[15];
  const float* bcq = (const float*)d_in[11];
  const float* bco = (const float*)d_in[17];
  const float* gamma = (const float*)d_in[18];
  const float* beta  = (const float*)d_in[19];
  const float* b1  = (const float*)d_in[21];
  const float* b2  = (const float*)d_in[23];
  float* out = (float*)d_out;
  char* ws = (char*)d_ws;
  const size_t MB = 1048576;

  // Workspace lifetime map (max 89 MB):
  //  0..20  wt[0..9]           prep -> end
  // 20..21  cb / cb2           prep_bias -> end
  // 21..29  xb (t1n alias)     prep -> gemm#1(res read); t1n: ln#1 -> gemm#2
  // 29..37  hb (t2n alias)     prep -> mega(A for K/V); t2n: ln#2 -> gemm#3
  // 37..61  qkv                mega -> self_attn (dead after)
  // 37..45  cqbuf              cq-gemm -> cross_attn   (recycles dead qkv)
  // 45..53  g4/f2out           gemm#1/#2/#3 -> ln#1/#2/#3 (recycles dead qkv)
  // 61..69  kbuf               mega(write) -> cross_attn
  // 69..77  vtbuf              mega(write) -> cross_attn
  // 77..85  attn               self_attn -> gemm#1; cross_attn -> gemm#2
  // 85..87  ptbuf              mega -> gemm#3
  // 87..89  w1bf               prep -> mega
  bf16_t* wt[10];
  for (int i = 0; i < 10; i++) wt[i] = (bf16_t*)(ws + (size_t)i * 2 * MB);
  float* cb      = (float*)(ws + 20 * MB);
  float* cb2     = (float*)(ws + 20 * MB + 32768);
  bf16_t* xb     = (bf16_t*)(ws + 21 * MB);
  bf16_t* hb     = (bf16_t*)(ws + 29 * MB);
  bf16_t* qkv    = (bf16_t*)(ws + 37 * MB);
  bf16_t* cqbuf  = (bf16_t*)(ws + 37 * MB);
  bf16_t* g4     = (bf16_t*)(ws + 45 * MB);
  bf16_t* kbuf   = (bf16_t*)(ws + 61 * MB);
  bf16_t* vtbuf  = (bf16_t*)(ws + 69 * MB);
  bf16_t* attn   = (bf16_t*)(ws + 77 * MB);
  bf16_t* ptbuf  = (bf16_t*)(ws + 85 * MB);
  bf16_t* w1bf   = (bf16_t*)(ws + 87 * MB);
  bf16_t* t1n    = xb;
  bf16_t* t2n    = hb;
  bf16_t* f2out  = g4;

  // prep: casts + weight transposes merged (one launch), then biases
  prep_main<<<14848, 256, 0, stream>>>(sp, (bf16_t*)ws, x, hh, W1f, xb, w1bf);
  prep_bias_kernel<<<32, 256, 0, stream>>>(bq, bk, bv, bck, bcv, bcq,
                                           wt[9], b1, b2, cb, cb2);

  // ALL independent MFMA work in one launch: qkv + P + K-proj + V-proj
  gemm_mega<<<1920, 256, 0, stream>>>(xb, wt[0], wt[9], w1bf, hb, wt[4], cb,
                                      qkv, ptbuf, kbuf, vtbuf);
  // self-attn standalone at its VALU/TRANS issue floor (~48us, R4-verified)
  self_attn_kernel<<<16384, 256, 0, stream>>>(qkv, attn);
  gemm_bf16<true, false><<<dim3(16, 32), 256, 0, stream>>>(attn, wt[3], bo, xb, g4, 1024);
  ln_kernel<bf16_t><<<4096, 256, 0, stream>>>(g4, gamma, beta, t1n);
  // cross-attn block: only the cq projection remains serial
  gemm_bf16<false, false><<<dim3(16, 32), 256, 0, stream>>>(t1n, wt[4], cb + 5120,
                                                            nullptr, cqbuf, 1024);
  cross_attn_mfma<<<dim3(128, 8), 256, 0, stream>>>(cqbuf, kbuf, vtbuf, attn);
  gemm_bf16<true, false><<<dim3(16, 32), 256, 0, stream>>>(attn, wt[7], bco, t1n, g4, 1024);
  ln_kernel<bf16_t><<<4096, 256, 0, stream>>>(g4, gamma, beta, t2n);
  // FFN collapsed: out = t2n @ P + (b1@W2 + b2) + t2n
  gemm_bf16<true, false><<<dim3(16, 32), 256, 0, stream>>>(t2n, ptbuf, cb2, t2n, f2out, 1024);
  ln_kernel<float><<<4096, 256, 0, stream>>>(f2out, gamma, beta, out);
}

// Round 8
// 367.072 us; speedup vs baseline: 1.0059x; 1.0059x over previous
//
#include <hip/hip_runtime.h>

typedef __bf16 bf16_t;
typedef bf16_t bf16x8 __attribute__((ext_vector_type(8)));
typedef bf16_t bf16x4 __attribute__((ext_vector_type(4)));
typedef float f32x4 __attribute__((ext_vector_type(4)));
typedef unsigned u32x4 __attribute__((ext_vector_type(4)));

// async global->LDS 16B per lane. LDS dest = wave-uniform base + lane*16
// (m97/m104): per-lane pointers must be linear in lane index.
__device__ __forceinline__ void async_copy16(const void* g, void* l) {
  __builtin_amdgcn_global_load_lds(
      (const __attribute__((address_space(1))) unsigned int*)(unsigned long long)g,
      (__attribute__((address_space(3))) unsigned int*)(unsigned int)(unsigned long long)l,
      16, 0, 0);
}

// guaranteed single-instruction exp2 / rcp
__device__ __forceinline__ float fast_exp2(float x) {
#if __has_builtin(__builtin_amdgcn_exp2f)
  return __builtin_amdgcn_exp2f(x);
#else
  float r;
  asm volatile("v_exp_f32 %0, %1\n\ts_nop 0" : "=v"(r) : "v"(x));
  return r;
#endif
}
__device__ __forceinline__ float fast_rcp(float x) {
#if __has_builtin(__builtin_amdgcn_rcpf)
  return __builtin_amdgcn_rcpf(x);
#else
  float r;
  asm volatile("v_rcp_f32 %0, %1\n\ts_nop 0" : "=v"(r) : "v"(x));
  return r;
#endif
}

__device__ __forceinline__ unsigned pack_bf16(float x, float y) {
  bf16_t lo = (bf16_t)x, hi = (bf16_t)y;
  unsigned short ul, uh;
  __builtin_memcpy(&ul, &lo, 2);
  __builtin_memcpy(&uh, &hi, 2);
  return (unsigned)ul | ((unsigned)uh << 16);
}

// Q-projection carries 1/8 (softmax scale) * log2e (exp->exp2 conversion)
#define QSCALE 0.180336688f

// ---------------- merged prep: 10 weight transposes + x/h/W1 bf16 cast ------
struct SrcPtrs { const float* p[10]; };
__global__ __launch_bounds__(256) void prep_main(
    SrcPtrs srcs, bf16_t* __restrict__ dstbase,
    const float* __restrict__ a, const float* __restrict__ b,
    const float* __restrict__ w1, bf16_t* __restrict__ dst1,
    bf16_t* __restrict__ dstw) {
  __shared__ float tile[32][33];
  int bid = blockIdx.x;
  int tid = threadIdx.x;
  if (bid < 10240) {
    int z = bid >> 10;
    int rem = bid & 1023;
    const float* src = srcs.p[z];
    bf16_t* dst = dstbase + (size_t)z * 1048576;
    float scale = (z == 0) ? QSCALE : ((z == 4) ? 0.03125f : 1.f);
    int bx = (rem & 31) * 32;   // n base
    int by = (rem >> 5) * 32;   // k base
    int tx = tid & 31, ty = tid >> 5;  // 32x8
#pragma unroll
    for (int i = 0; i < 32; i += 8)
      tile[ty + i][tx] = src[(size_t)(by + ty + i) * 1024 + bx + tx];
    __syncthreads();
#pragma unroll
    for (int i = 0; i < 32; i += 8)
      dst[(size_t)(bx + ty + i) * 1024 + by + tx] = (bf16_t)(tile[tx][ty + i] * scale);
  } else {
    int i = ((bid - 10240) * 256 + tid) * 8;  // [0, 9M)
    const float* s;
    bf16_t* d;
    if (i < 4194304) { s = a + i; d = dst1 + i; }
    else if (i < 8388608) { s = b + i - 4194304; d = dst1 + i; }
    else { s = w1 + i - 8388608; d = dstw + (i - 8388608); }
    float4 u = *(const float4*)s;
    float4 v = *(const float4*)(s + 4);
    bf16x8 o;
    o[0]=(bf16_t)u.x; o[1]=(bf16_t)u.y; o[2]=(bf16_t)u.z; o[3]=(bf16_t)u.w;
    o[4]=(bf16_t)v.x; o[5]=(bf16_t)v.y; o[6]=(bf16_t)v.z; o[7]=(bf16_t)v.w;
    *(bf16x8*)d = o;
  }
}

// --- bias concat [q|k|v|ck|cv|cq|zeros] x1024 + fused FFN bias (blk 28-31) --
__global__ __launch_bounds__(256) void prep_bias_kernel(
    const float* __restrict__ bq, const float* __restrict__ bk,
    const float* __restrict__ bv, const float* __restrict__ bck,
    const float* __restrict__ bcv, const float* __restrict__ bcq,
    const bf16_t* __restrict__ wt9, const float* __restrict__ b1,
    const float* __restrict__ b2, float* __restrict__ cb,
    float* __restrict__ cb2) {
  int bid = blockIdx.x;
  if (bid < 28) {
    int i = bid * 256 + threadIdx.x;
    if (i < 1024) cb[i] = bq[i] * QSCALE;
    else if (i < 2048) cb[i] = bk[i - 1024];
    else if (i < 3072) cb[i] = bv[i - 2048];
    else if (i < 4096) cb[i] = bck[i - 3072];
    else if (i < 5120) cb[i] = bcv[i - 4096];
    else if (i < 6144) cb[i] = bcq[i - 5120] * 0.03125f;
    else cb[i] = 0.f;  // zeros for the P-GEMM bias
  } else {
    // cb2[n] = sum_h b1[h]*W2[h][n] + b2[n];  wt9[n][h] = W2[h][n]
    int n = (bid - 28) * 256 + threadIdx.x;
    const bf16_t* row = wt9 + (size_t)n * 1024;
    float acc = 0.f;
#pragma unroll 4
    for (int h = 0; h < 1024; h += 8) {
      bf16x8 v = *(const bf16x8*)(row + h);
      float4 ba = *(const float4*)(b1 + h);
      float4 bb = *(const float4*)(b1 + h + 4);
      acc += ba.x*(float)v[0] + ba.y*(float)v[1] + ba.z*(float)v[2] + ba.w*(float)v[3]
           + bb.x*(float)v[4] + bb.y*(float)v[5] + bb.z*(float)v[6] + bb.w*(float)v[7];
    }
    cb2[n] = acc + b2[n];
  }
}

// ---------------- shared GEMM core: C[*,ldC] = A[*,1024] @ Bt[*,1024]^T -----
// Generalized over BM (R7: all GEMMs were occupancy-limited at ~19% by the
// 128-row tile's 64-AGPR accumulator; BM=64 halves acc regs and doubles
// blocks/CU). Wave map: BM=128,BN=128 -> 2x2x(64x64); BM=128,BN=64 -> 4x1
// stacked; BM=64 -> 2x2x(32 x BN/2).
template <int BM, int BN, int MI, int NI, bool HAS_RES, bool TRANS_OUT, bool DBUF>
__device__ __forceinline__ void gemm_core(
    const bf16_t* __restrict__ A, const bf16_t* __restrict__ Bt,
    const float* __restrict__ bias, const bf16_t* __restrict__ res,
    bf16_t* __restrict__ C, int ldC, int bm, int bn,
    bf16_t* As, bf16_t* Bs) {
  constexpr int ASZ = BM * 64, BSZ = BN * 64;
  int tid = threadIdx.x;
  int w = tid >> 6, lane = tid & 63;
  int fm = lane & 15, fq = lane >> 4;
  int wm, wn;
  if (BM == 128 && BN == 128) { wm = (w >> 1) * 64; wn = (w & 1) * 64; }
  else if (BM == 128) { wm = w * 32; wn = 0; }
  else { wm = (w >> 1) * 32; wn = (w & 1) * (BN / 2); }
  f32x4 acc[MI][NI] = {};

  auto stage = [&](int kt, int half) {
    bf16_t* Ad = DBUF ? As + half * ASZ : As;
    bf16_t* Bd = DBUF ? Bs + half * BSZ : Bs;
#pragma unroll
    for (int i = 0; i < BM / 32; i++) {  // A: BM rows x 8 chunks
      int c = i * 256 + tid;
      int row = c >> 3, skg = (c & 7) ^ (row & 7);
      async_copy16(A + (size_t)(bm + row) * 1024 + kt + skg * 8, &Ad[c * 8]);
    }
#pragma unroll
    for (int i = 0; i < BN / 32; i++) {  // B: BN rows x 8 chunks
      int c = i * 256 + tid;
      int row = c >> 3, skg = (c & 7) ^ (row & 7);
      async_copy16(Bt + (size_t)(bn + row) * 1024 + kt + skg * 8, &Bd[c * 8]);
    }
  };
  auto compute = [&](int half) {
    const bf16_t* Ac = DBUF ? As + half * ASZ : As;
    const bf16_t* Bc = DBUF ? Bs + half * BSZ : Bs;
#pragma unroll
    for (int ks = 0; ks < 2; ks++) {
      bf16x8 af[MI], bfr[NI];
      int kg = ks * 4 + fq;
#pragma unroll
      for (int mi = 0; mi < MI; mi++) {
        int row = wm + mi * 16 + fm;
        af[mi] = *(const bf16x8*)&Ac[row * 64 + ((kg ^ (row & 7)) * 8)];
      }
#pragma unroll
      for (int ni = 0; ni < NI; ni++) {
        int row = wn + ni * 16 + fm;
        bfr[ni] = *(const bf16x8*)&Bc[row * 64 + ((kg ^ (row & 7)) * 8)];
      }
#pragma unroll
      for (int mi = 0; mi < MI; mi++)
#pragma unroll
        for (int ni = 0; ni < NI; ni++)
          acc[mi][ni] = __builtin_amdgcn_mfma_f32_16x16x32_bf16(
              af[mi], bfr[ni], acc[mi][ni], 0, 0, 0);
    }
  };

  if (DBUF) {
    stage(0, 0);
    __syncthreads();  // tile 0 resident
#pragma unroll
    for (int t = 0; t < 16; t++) {
      if (t < 15) stage((t + 1) * 64, (t + 1) & 1);  // prefetch next half
      compute(t & 1);
      __syncthreads();  // drains vmcnt(0) AFTER compute; frees half t&1
    }
  } else {
    for (int kt = 0; kt < 1024; kt += 64) {
      stage(kt, 0);
      __syncthreads();  // drains vmcnt(0): copies visible
      compute(0);
      __syncthreads();  // protect LDS reuse
    }
  }

#pragma unroll
  for (int mi = 0; mi < MI; mi++) {
#pragma unroll
    for (int ni = 0; ni < NI; ni++) {
      int col = bn + wn + ni * 16 + fm;
      float bv = bias[col];
      if (TRANS_OUT) {
        int rowb = bm + wm + mi * 16 + fq * 4;
        bf16x4 w4;
#pragma unroll
        for (int r = 0; r < 4; r++) w4[r] = (bf16_t)(acc[mi][ni][r] + bv);
        *(bf16x4*)&C[(size_t)col * ldC + rowb] = w4;  // C^T: ldC = M
      } else {
#pragma unroll
        for (int r = 0; r < 4; r++) {
          int row = bm + wm + mi * 16 + fq * 4 + r;  // C/D map (m89/m91)
          float v = acc[mi][ni][r] + bv;
          if (HAS_RES) v += (float)res[(size_t)row * ldC + col];
          C[(size_t)row * ldC + col] = (bf16_t)v;
        }
      }
    }
  }
}

// ---------------- mid GEMM: M=4096, N=1024, 64x64 DBUF tiles ----------------
// 1024 blocks = 4/CU (was 512 = 2/CU grid-capped). XCD map: xcd owns a
// contiguous 512-row A-slice (1MB) x all N; A(1MB)+B(2MB) = 3MB fits L2.
template <bool HAS_RES, bool TRANS_OUT>
__global__ __launch_bounds__(256) void gemm_bf16(
    const bf16_t* __restrict__ A, const bf16_t* __restrict__ Bt,
    const float* __restrict__ bias, const bf16_t* __restrict__ res,
    bf16_t* __restrict__ C, int ldC) {
  __shared__ bf16_t As[2 * 64 * 64];  // 16 KB
  __shared__ bf16_t Bs[2 * 64 * 64];  // 16 KB
  int lin = blockIdx.x;
  int xcd = lin & 7, idx = lin >> 3;          // idx in [0,128)
  int ly = idx >> 4, lx = idx & 15;           // 8 x 16
  int bm = (xcd * 8 + ly) * 64;
  int bn = lx * 64;
  gemm_core<64, 64, 2, 2, HAS_RES, TRANS_OUT, true>(A, Bt, bias, res, C, ldC,
                                                    bm, bn, As, Bs);
}

// ======== MEGA-GEMM: all MFMA work that depends only on prep, ONE launch ====
// All segments 64x128 tiles (acc 32 regs, 24KB LDS -> 6 blocks/CU; R7's
// 128-row tiles were register-capped at ~3):
//   [0,1536):    qkv C[4096][3072] = xb @ [Wq|Wk|Wv]
//   [1536,1664): Pt[1024][1024]    = wt9 @ w1bf^T
//   [1664,2176): kbuf[4096][1024]  = hb @ Wck
//   [2176,2688): vt[1024][4096]    = (hb @ Wcv)^T
// Segment bases all 0 mod 8 -> per-segment xcd = lin&7 stays valid.
__global__ __launch_bounds__(256) void gemm_mega(
    const bf16_t* __restrict__ xb, const bf16_t* __restrict__ wt0,
    const bf16_t* __restrict__ wt9, const bf16_t* __restrict__ w1bf,
    const bf16_t* __restrict__ hb, const bf16_t* __restrict__ wt4,
    const float* __restrict__ cb, bf16_t* __restrict__ qkv,
    bf16_t* __restrict__ pt, bf16_t* __restrict__ kbuf,
    bf16_t* __restrict__ vt) {
  __shared__ bf16_t As[64 * 64];   // 8 KB
  __shared__ bf16_t Bs[128 * 64];  // 16 KB
  int bid = blockIdx.x;
  if (bid < 1536) {           // qkv: 64 bm x 24 bn; XCD: 4 M-groups x 2 N-grps
    int xcd = bid & 7, idx = bid >> 3;        // idx in [0,192)
    int ly = idx / 12, lx = idx - ly * 12;    // 16 x 12
    int bm = ((xcd >> 1) * 16 + ly) * 64;
    int bn = ((xcd & 1) * 12 + lx) * 128;
    gemm_core<64, 128, 2, 4, false, false, false>(xb, wt0, cb, nullptr, qkv,
                                                  3072, bm, bn, As, Bs);
  } else if (bid < 1664) {    // P: 16 bm x 8 bn
    int idx = bid - 1536;
    gemm_core<64, 128, 2, 4, false, false, false>(wt9, w1bf, cb + 6144, nullptr,
                                                  pt, 1024, (idx & 15) * 64,
                                                  (idx >> 4) * 128, As, Bs);
  } else if (bid < 2176) {    // K-proj: xcd owns 512-row slice x all 8 bn
    int idx = bid - 1664;
    int xcd = idx & 7, j = idx >> 3;          // j in [0,64)
    int bm = (xcd * 8 + (j >> 3)) * 64;
    int bn = (j & 7) * 128;
    gemm_core<64, 128, 2, 4, false, false, false>(hb, wt4 + 1048576, cb + 3072,
                                                  nullptr, kbuf, 1024, bm, bn,
                                                  As, Bs);
  } else {                    // V-proj: (hb @ Wcv)^T, ldC = 4096
    int idx = bid - 2176;
    int xcd = idx & 7, j = idx >> 3;
    int bm = (xcd * 8 + (j >> 3)) * 64;
    int bn = (j & 7) * 128;
    gemm_core<64, 128, 2, 4, false, true, false>(hb, wt4 + 2097152, cb + 4096,
                                                 nullptr, vt, 4096, bm, bn,
                                                 As, Bs);
  }
}

// ---------------- self-attn core: causal softmax over C=64 channels ---------
// ZERO-LDS scalar-path form (R4-verified ~48us = VALU/TRANS issue floor).
__global__ __launch_bounds__(256) void self_attn_kernel(
    const bf16_t* __restrict__ QKV, bf16_t* __restrict__ O) {
  int tid = threadIdx.x;
  int lane = tid & 63;
  int unit = __builtin_amdgcn_readfirstlane(blockIdx.x * 4 + (tid >> 6));
  int m = unit >> 4, h = unit & 15;
  size_t base = (size_t)m * 3072 + h * 64;
  size_t iq = base + lane;
  float qv = (float)QKV[iq];                 // (1/8)*log2e pre-folded
  float kown = (float)QKV[iq + 1024];        // K[lane] (diagonal term)
  float vown = (float)QKV[iq + 2048];        // V[lane]
  const u32x4* Krow = (const u32x4*)(QKV + base + 1024);
  const u32x4* Vrow = (const u32x4*)(QKV + base + 2048);
  u32x4 K4[8], V4[8];
#pragma unroll
  for (int i = 0; i < 8; i++) { K4[i] = Krow[i]; V4[i] = Vrow[i]; }
  float l0 = 0.f, l1 = 0.f, o0 = 0.f, o1 = 0.f;
#pragma unroll
  for (int p = 0; p < 32; p++) {
    unsigned kw = K4[p >> 2][p & 3];   // scalar: (k_{2p}, k_{2p+1}) bf16 pair
    unsigned vw = V4[p >> 2][p & 3];
    float k0 = __uint_as_float(kw << 16);          // SALU
    float k1 = __uint_as_float(kw & 0xffff0000u);  // SALU
    float v0 = __uint_as_float(vw << 16);
    float v1 = __uint_as_float(vw & 0xffff0000u);
    float e0 = fast_exp2(qv * k0);
    float e1 = fast_exp2(qv * k1);
    bool c = lane >= 2 * p + 1;        // ONE cmp; excludes even-lane diagonal
    e0 = c ? e0 : 0.f;
    e1 = c ? e1 : 0.f;
    l0 += e0; o0 = fmaf(e0, v0, o0);
    l1 += e1; o1 = fmaf(e1, v1, o1);
  }
  // even-lane diagonal (k == lane, excluded by the strict shared mask)
  float ed = fast_exp2(qv * kown);
  ed = ((lane & 1) == 0) ? ed : 0.f;
  float l = (l0 + l1) + ed;
  float o = fmaf(ed, vown, o0 + o1);
  O[(size_t)m * 1024 + h * 64 + lane] = (bf16_t)(o * fast_rcp(l));
}

// ---------------- cross-attn, MFMA flash ------------------------------------
__global__ __launch_bounds__(256) void cross_attn_mfma(
    const bf16_t* __restrict__ Q, const bf16_t* __restrict__ Kb,
    const bf16_t* __restrict__ Vt, bf16_t* __restrict__ O) {
  __shared__ bf16_t Ks[64 * 64];
  __shared__ bf16_t Vs[64 * 64];
  int tid = threadIdx.x;
  int w = tid >> 6, lane = tid & 63;
  int fm = lane & 15, fq = lane >> 4;
  int bh = blockIdx.x;
  int b = bh >> 4, h = bh & 15;
  int q0 = blockIdx.y * 64 + w * 16;
  const bf16_t* Qp = Q + (size_t)(b * 512 + q0 + fm) * 1024 + h * 64 + fq * 8;
  bf16x8 qf0 = *(const bf16x8*)Qp;
  bf16x8 qf1 = *(const bf16x8*)(Qp + 32);
  f32x4 o[4] = {};  // O^T tiles ct: lane holds O^T[c=ct*16+fq*4+r][q=fm]
  float mx = -1e30f, l = 0.f;
  for (int k0 = 0; k0 < 512; k0 += 64) {
    __syncthreads();  // previous tile's LDS reads complete
#pragma unroll
    for (int i = 0; i < 2; i++) {  // 64 rows x 8 chunks, XOR swizzle
      int c = i * 256 + tid;
      int row = c >> 3, kg = (c & 7) ^ (row & 7);
      async_copy16(Kb + (size_t)(b * 512 + k0 + row) * 1024 + h * 64 + kg * 8,
                   &Ks[c * 8]);
      async_copy16(Vt + (size_t)(h * 64 + row) * 4096 + b * 512 + k0 + kg * 8,
                   &Vs[c * 8]);
    }
    __syncthreads();  // drain global_load_lds
    // S^T tiles mt: lane holds S^T[k=mt*16+fq*4+r][q=fm]
    f32x4 s[4] = {};
#pragma unroll
    for (int mt = 0; mt < 4; mt++) {
      int row = mt * 16 + fm;
#pragma unroll
      for (int f = 0; f < 2; f++) {
        int kg = f * 4 + fq;
        bf16x8 kf = *(const bf16x8*)&Ks[row * 64 + ((kg ^ (row & 7)) * 8)];
        s[mt] = __builtin_amdgcn_mfma_f32_16x16x32_bf16(
            kf, (f ? qf1 : qf0), s[mt], 0, 0, 0);
      }
    }
    // online softmax (stats per q=fm, replicated across quads)
    float smax = -1e30f;
#pragma unroll
    for (int mt = 0; mt < 4; mt++)
#pragma unroll
      for (int r = 0; r < 4; r++) smax = fmaxf(smax, s[mt][r]);
    smax = fmaxf(smax, __shfl_xor(smax, 16, 64));
    smax = fmaxf(smax, __shfl_xor(smax, 32, 64));
    float nm = fmaxf(mx, smax);
    float corr = __expf(mx - nm);
    float ladd = 0.f;
    unsigned pk0[4], pk1[4];
#pragma unroll
    for (int mt = 0; mt < 4; mt++) {
      float p0 = __expf(s[mt][0] - nm);
      float p1 = __expf(s[mt][1] - nm);
      float p2 = __expf(s[mt][2] - nm);
      float p3 = __expf(s[mt][3] - nm);
      ladd += (p0 + p1) + (p2 + p3);
      pk0[mt] = pack_bf16(p0, p1);
      pk1[mt] = pack_bf16(p2, p3);
    }
    ladd += __shfl_xor(ladd, 16, 64);
    ladd += __shfl_xor(ladd, 32, 64);
    l = l * corr + ladd;
#pragma unroll
    for (int ct = 0; ct < 4; ct++)
#pragma unroll
      for (int r = 0; r < 4; r++) o[ct][r] *= corr;
    union U { unsigned u[4]; bf16x8 v; } pf[2];
    int sl0 = ((fq & 1) * 2) * 16 + fm;
    int sl1 = sl0 + 16;
    bool hi = fq >= 2;
#pragma unroll
    for (int f = 0; f < 2; f++) {
      unsigned a0 = (unsigned)__shfl((int)pk0[f * 2],     sl0, 64);
      unsigned b0 = (unsigned)__shfl((int)pk0[f * 2 + 1], sl0, 64);
      unsigned a1 = (unsigned)__shfl((int)pk1[f * 2],     sl0, 64);
      unsigned b1 = (unsigned)__shfl((int)pk1[f * 2 + 1], sl0, 64);
      unsigned a2 = (unsigned)__shfl((int)pk0[f * 2],     sl1, 64);
      unsigned b2 = (unsigned)__shfl((int)pk0[f * 2 + 1], sl1, 64);
      unsigned a3 = (unsigned)__shfl((int)pk1[f * 2],     sl1, 64);
      unsigned b3 = (unsigned)__shfl((int)pk1[f * 2 + 1], sl1, 64);
      pf[f].u[0] = hi ? b0 : a0;
      pf[f].u[1] = hi ? b1 : a1;
      pf[f].u[2] = hi ? b2 : a2;
      pf[f].u[3] = hi ? b3 : a3;
    }
#pragma unroll
    for (int ct = 0; ct < 4; ct++) {
      int row = ct * 16 + fm;
#pragma unroll
      for (int f = 0; f < 2; f++) {
        int kg = f * 4 + fq;
        bf16x8 vf = *(const bf16x8*)&Vs[row * 64 + ((kg ^ (row & 7)) * 8)];
        o[ct] = __builtin_amdgcn_mfma_f32_16x16x32_bf16(vf, pf[f].v, o[ct], 0, 0, 0);
      }
    }
    mx = nm;
  }
  float inv = 1.f / l;
  bf16_t* Op = O + (size_t)(b * 512 + q0 + fm) * 1024 + h * 64 + fq * 4;
#pragma unroll
  for (int ct = 0; ct < 4; ct++) {
    bf16x4 w4;
    w4[0] = (bf16_t)(o[ct][0] * inv);
    w4[1] = (bf16_t)(o[ct][1] * inv);
    w4[2] = (bf16_t)(o[ct][2] * inv);
    w4[3] = (bf16_t)(o[ct][3] * inv);
    *(bf16x4*)(Op + ct * 16) = w4;
  }
}

// ---------------- LayerNorm D=1024, bf16 in, OutT out -----------------------
template <typename OutT>
__global__ __launch_bounds__(256) void ln_kernel(
    const bf16_t* __restrict__ X, const float* __restrict__ gamma,
    const float* __restrict__ beta, OutT* __restrict__ Y) {
  __shared__ float red[8];
  int row = blockIdx.x;
  int tid = threadIdx.x;
  bf16x4 x4 = *(const bf16x4*)(X + (size_t)row * 1024 + tid * 4);
  float4 v = {(float)x4[0], (float)x4[1], (float)x4[2], (float)x4[3]};
  float s = (v.x + v.y) + (v.z + v.w);
  float ss = fmaf(v.x, v.x, fmaf(v.y, v.y, fmaf(v.z, v.z, v.w * v.w)));
#pragma unroll
  for (int off = 32; off > 0; off >>= 1) {
    s  += __shfl_down(s, off, 64);
    ss += __shfl_down(ss, off, 64);
  }
  if ((tid & 63) == 0) { red[tid >> 6] = s; red[4 + (tid >> 6)] = ss; }
  __syncthreads();
  float S  = (red[0] + red[1]) + (red[2] + red[3]);
  float SS = (red[4] + red[5]) + (red[6] + red[7]);
  float mu = S * (1.f / 1024.f);
  float var = SS * (1.f / 1024.f) - mu * mu;
  float inv = rsqrtf(var + 1e-5f);
  float4 g = *(const float4*)(gamma + tid * 4);
  float4 b = *(const float4*)(beta + tid * 4);
  float r0 = (v.x - mu) * inv * g.x + b.x;
  float r1 = (v.y - mu) * inv * g.y + b.y;
  float r2 = (v.z - mu) * inv * g.z + b.z;
  float r3 = (v.w - mu) * inv * g.w + b.w;
  OutT* yp = Y + (size_t)row * 1024 + tid * 4;
  yp[0] = (OutT)r0; yp[1] = (OutT)r1; yp[2] = (OutT)r2; yp[3] = (OutT)r3;
}

extern "C" void kernel_launch(void* const* d_in, const int* in_sizes, int n_in,
                              void* d_out, int out_size, void* d_ws, size_t ws_size,
                              hipStream_t stream) {
  (void)in_sizes; (void)n_in; (void)out_size; (void)ws_size;
  const float* x  = (const float*)d_in[0];
  const float* hh = (const float*)d_in[1];
  SrcPtrs sp;
  sp.p[0] = (const float*)d_in[2];  sp.p[1] = (const float*)d_in[4];
  sp.p[2] = (const float*)d_in[6];  sp.p[3] = (const float*)d_in[8];
  sp.p[4] = (const float*)d_in[10]; sp.p[5] = (const float*)d_in[12];
  sp.p[6] = (const float*)d_in[14]; sp.p[7] = (const float*)d_in[16];
  sp.p[8] = (const float*)d_in[20]; sp.p[9] = (const float*)d_in[22];
  const float* W1f = (const float*)d_in[20];
  const float* bq  = (const float*)d_in[3];
  const float* bk  = (const float*)d_in[5];
  const float* bv  = (const float*)d_in[7];
  const float* bo  = (const float*)d_in[9];
  const float* bck = (const float*)d_in[13];
  const float* bcv = (const float*)d_in[15];
  const float* bcq = (const float*)d_in[11];
  const float* bco = (const float*)d_in[17];
  const float* gamma = (const float*)d_in[18];
  const float* beta  = (const float*)d_in[19];
  const float* b1  = (const float*)d_in[21];
  const float* b2  = (const float*)d_in[23];
  float* out = (float*)d_out;
  char* ws = (char*)d_ws;
  const size_t MB = 1048576;

  // Workspace lifetime map (max 89 MB):
  //  0..20  wt[0..9]           prep -> end
  // 20..21  cb / cb2           prep_bias -> end
  // 21..29  xb (t1n alias)     prep -> gemm#1(res read); t1n: ln#1 -> gemm#2
  // 29..37  hb (t2n alias)     prep -> mega(A for K/V); t2n: ln#2 -> gemm#3
  // 37..61  qkv                mega -> self_attn (dead after)
  // 37..45  cqbuf              cq-gemm -> cross_attn   (recycles dead qkv)
  // 45..53  g4/f2out           gemm#1/#2/#3 -> ln#1/#2/#3 (recycles dead qkv)
  // 61..69  kbuf               mega(write) -> cross_attn
  // 69..77  vtbuf              mega(write) -> cross_attn
  // 77..85  attn               self_attn -> gemm#1; cross_attn -> gemm#2
  // 85..87  ptbuf              mega -> gemm#3
  // 87..89  w1bf               prep -> mega
  bf16_t* wt[10];
  for (int i = 0; i < 10; i++) wt[i] = (bf16_t*)(ws + (size_t)i * 2 * MB);
  float* cb      = (float*)(ws + 20 * MB);
  float* cb2     = (float*)(ws + 20 * MB + 32768);
  bf16_t* xb     = (bf16_t*)(ws + 21 * MB);
  bf16_t* hb     = (bf16_t*)(ws + 29 * MB);
  bf16_t* qkv    = (bf16_t*)(ws + 37 * MB);
  bf16_t* cqbuf  = (bf16_t*)(ws + 37 * MB);
  bf16_t* g4     = (bf16_t*)(ws + 45 * MB);
  bf16_t* kbuf   = (bf16_t*)(ws + 61 * MB);
  bf16_t* vtbuf  = (bf16_t*)(ws + 69 * MB);
  bf16_t* attn   = (bf16_t*)(ws + 77 * MB);
  bf16_t* ptbuf  = (bf16_t*)(ws + 85 * MB);
  bf16_t* w1bf   = (bf16_t*)(ws + 87 * MB);
  bf16_t* t1n    = xb;
  bf16_t* t2n    = hb;
  bf16_t* f2out  = g4;

  // prep: casts + weight transposes merged (one launch), then biases
  prep_main<<<14848, 256, 0, stream>>>(sp, (bf16_t*)ws, x, hh, W1f, xb, w1bf);
  prep_bias_kernel<<<32, 256, 0, stream>>>(bq, bk, bv, bck, bcv, bcq,
                                           wt[9], b1, b2, cb, cb2);

  // ALL independent MFMA work in one launch: qkv + P + K-proj + V-proj
  gemm_mega<<<2688, 256, 0, stream>>>(xb, wt[0], wt[9], w1bf, hb, wt[4], cb,
                                      qkv, ptbuf, kbuf, vtbuf);
  // self-attn standalone at its VALU/TRANS issue floor (~48us, R4-verified)
  self_attn_kernel<<<16384, 256, 0, stream>>>(qkv, attn);
  gemm_bf16<true, false><<<1024, 256, 0, stream>>>(attn, wt[3], bo, xb, g4, 1024);
  ln_kernel<bf16_t><<<4096, 256, 0, stream>>>(g4, gamma, beta, t1n);
  // cross-attn block: only the cq projection remains serial
  gemm_bf16<false, false><<<1024, 256, 0, stream>>>(t1n, wt[4], cb + 5120,
                                                    nullptr, cqbuf, 1024);
  cross_attn_mfma<<<dim3(128, 8), 256, 0, stream>>>(cqbuf, kbuf, vtbuf, attn);
  gemm_bf16<true, false><<<1024, 256, 0, stream>>>(attn, wt[7], bco, t1n, g4, 1024);
  ln_kernel<bf16_t><<<4096, 256, 0, stream>>>(g4, gamma, beta, t2n);
  // FFN collapsed: out = t2n @ P + (b1@W2 + b2) + t2n
  gemm_bf16<true, false><<<1024, 256, 0, stream>>>(t2n, ptbuf, cb2, t2n, f2out, 1024);
  ln_kernel<float><<<4096, 256, 0, stream>>>(f2out, gamma, beta, out);
}

// Round 10
// 366.693 us; speedup vs baseline: 1.0069x; 1.0010x over previous
//
#include <hip/hip_runtime.h>

typedef __bf16 bf16_t;
typedef bf16_t bf16x8 __attribute__((ext_vector_type(8)));
typedef bf16_t bf16x4 __attribute__((ext_vector_type(4)));
typedef float f32x4 __attribute__((ext_vector_type(4)));
typedef unsigned u32x4 __attribute__((ext_vector_type(4)));

// async global->LDS 16B per lane. LDS dest = wave-uniform base + lane*16
// (m97/m104): per-lane pointers must be linear in lane index.
__device__ __forceinline__ void async_copy16(const void* g, void* l) {
  __builtin_amdgcn_global_load_lds(
      (const __attribute__((address_space(1))) unsigned int*)(unsigned long long)g,
      (__attribute__((address_space(3))) unsigned int*)(unsigned int)(unsigned long long)l,
      16, 0, 0);
}

// counted vmcnt wait (compile-time literal) — T4: never drain to 0 mid-loop
template <int N> __device__ __forceinline__ void vm_wait() {
  if constexpr (N == 0) asm volatile("s_waitcnt vmcnt(0)" ::: "memory");
  else if constexpr (N == 4) asm volatile("s_waitcnt vmcnt(4)" ::: "memory");
  else if constexpr (N == 6) asm volatile("s_waitcnt vmcnt(6)" ::: "memory");
  else if constexpr (N == 8) asm volatile("s_waitcnt vmcnt(8)" ::: "memory");
}
__device__ __forceinline__ void raw_barrier() {
  asm volatile("s_barrier" ::: "memory");
}

// guaranteed single-instruction exp2 / rcp
__device__ __forceinline__ float fast_exp2(float x) {
#if __has_builtin(__builtin_amdgcn_exp2f)
  return __builtin_amdgcn_exp2f(x);
#else
  float r;
  asm volatile("v_exp_f32 %0, %1\n\ts_nop 0" : "=v"(r) : "v"(x));
  return r;
#endif
}
__device__ __forceinline__ float fast_rcp(float x) {
#if __has_builtin(__builtin_amdgcn_rcpf)
  return __builtin_amdgcn_rcpf(x);
#else
  float r;
  asm volatile("v_rcp_f32 %0, %1\n\ts_nop 0" : "=v"(r) : "v"(x));
  return r;
#endif
}

__device__ __forceinline__ unsigned pack_bf16(float x, float y) {
  bf16_t lo = (bf16_t)x, hi = (bf16_t)y;
  unsigned short ul, uh;
  __builtin_memcpy(&ul, &lo, 2);
  __builtin_memcpy(&uh, &hi, 2);
  return (unsigned)ul | ((unsigned)uh << 16);
}

// Q-projection carries 1/8 (softmax scale) * log2e (exp->exp2 conversion)
#define QSCALE 0.180336688f

// ---------------- merged prep: 10 weight transposes + x/h/W1 bf16 cast ------
struct SrcPtrs { const float* p[10]; };
__global__ __launch_bounds__(256) void prep_main(
    SrcPtrs srcs, bf16_t* __restrict__ dstbase,
    const float* __restrict__ a, const float* __restrict__ b,
    const float* __restrict__ w1, bf16_t* __restrict__ dst1,
    bf16_t* __restrict__ dstw) {
  __shared__ float tile[32][33];
  int bid = blockIdx.x;
  int tid = threadIdx.x;
  if (bid < 10240) {
    int z = bid >> 10;
    int rem = bid & 1023;
    const float* src = srcs.p[z];
    bf16_t* dst = dstbase + (size_t)z * 1048576;
    float scale = (z == 0) ? QSCALE : ((z == 4) ? 0.03125f : 1.f);
    int bx = (rem & 31) * 32;   // n base
    int by = (rem >> 5) * 32;   // k base
    int tx = tid & 31, ty = tid >> 5;  // 32x8
#pragma unroll
    for (int i = 0; i < 32; i += 8)
      tile[ty + i][tx] = src[(size_t)(by + ty + i) * 1024 + bx + tx];
    __syncthreads();
#pragma unroll
    for (int i = 0; i < 32; i += 8)
      dst[(size_t)(bx + ty + i) * 1024 + by + tx] = (bf16_t)(tile[tx][ty + i] * scale);
  } else {
    int i = ((bid - 10240) * 256 + tid) * 8;  // [0, 9M)
    const float* s;
    bf16_t* d;
    if (i < 4194304) { s = a + i; d = dst1 + i; }
    else if (i < 8388608) { s = b + i - 4194304; d = dst1 + i; }
    else { s = w1 + i - 8388608; d = dstw + (i - 8388608); }
    float4 u = *(const float4*)s;
    float4 v = *(const float4*)(s + 4);
    bf16x8 o;
    o[0]=(bf16_t)u.x; o[1]=(bf16_t)u.y; o[2]=(bf16_t)u.z; o[3]=(bf16_t)u.w;
    o[4]=(bf16_t)v.x; o[5]=(bf16_t)v.y; o[6]=(bf16_t)v.z; o[7]=(bf16_t)v.w;
    *(bf16x8*)d = o;
  }
}

// --- bias concat [q|k|v|ck|cv|cq|zeros] x1024 + fused FFN bias (blk 28-31) --
__global__ __launch_bounds__(256) void prep_bias_kernel(
    const float* __restrict__ bq, const float* __restrict__ bk,
    const float* __restrict__ bv, const float* __restrict__ bck,
    const float* __restrict__ bcv, const float* __restrict__ bcq,
    const bf16_t* __restrict__ wt9, const float* __restrict__ b1,
    const float* __restrict__ b2, float* __restrict__ cb,
    float* __restrict__ cb2) {
  int bid = blockIdx.x;
  if (bid < 28) {
    int i = bid * 256 + threadIdx.x;
    if (i < 1024) cb[i] = bq[i] * QSCALE;
    else if (i < 2048) cb[i] = bk[i - 1024];
    else if (i < 3072) cb[i] = bv[i - 2048];
    else if (i < 4096) cb[i] = bck[i - 3072];
    else if (i < 5120) cb[i] = bcv[i - 4096];
    else if (i < 6144) cb[i] = bcq[i - 5120] * 0.03125f;
    else cb[i] = 0.f;  // zeros for the P-GEMM bias
  } else {
    // cb2[n] = sum_h b1[h]*W2[h][n] + b2[n];  wt9[n][h] = W2[h][n]
    int n = (bid - 28) * 256 + threadIdx.x;
    const bf16_t* row = wt9 + (size_t)n * 1024;
    float acc = 0.f;
#pragma unroll 4
    for (int h = 0; h < 1024; h += 8) {
      bf16x8 v = *(const bf16x8*)(row + h);
      float4 ba = *(const float4*)(b1 + h);
      float4 bb = *(const float4*)(b1 + h + 4);
      acc += ba.x*(float)v[0] + ba.y*(float)v[1] + ba.z*(float)v[2] + ba.w*(float)v[3]
           + bb.x*(float)v[4] + bb.y*(float)v[5] + bb.z*(float)v[6] + bb.w*(float)v[7];
    }
    cb2[n] = acc + b2[n];
  }
}

// ---------------- shared GEMM core: C[*,ldC] = A[*,1024] @ Bt[*,1024]^T -----
// DBUF=true: counted-vmcnt 2-phase (T3+T4 minimum). Per K-step:
//   stage(t+1) -> s_waitcnt vmcnt(LPS)  [own stage(t) done; t+1 IN FLIGHT]
//   -> s_barrier [all waves' stage(t) done] -> compute(t)
//   -> lgkmcnt(0) -> s_barrier [buffer t%2 free].
// Unlike __syncthreads (vmcnt(0) drain), stage(t+1)'s loads span both
// barriers and all of compute(t) — exposed latency ~0 in steady state.
// Correctness per m218/m201: per-wave vmcnt + barrier => all stage(t) loads
// landed; trailing barrier separates compute(t) readers from stage(t+2).
// R9 BUG (fixed): stage()'s first arg is the K element offset -> (t+1)*64,
// NOT t+1. R9 passed t+1 and read garbage K-slices.
template <int BM, int BN, int MI, int NI, bool HAS_RES, bool TRANS_OUT, bool DBUF>
__device__ __forceinline__ void gemm_core(
    const bf16_t* __restrict__ A, const bf16_t* __restrict__ Bt,
    const float* __restrict__ bias, const bf16_t* __restrict__ res,
    bf16_t* __restrict__ C, int ldC, int bm, int bn,
    bf16_t* As, bf16_t* Bs) {
  constexpr int ASZ = BM * 64, BSZ = BN * 64;
  constexpr int LPS = BM / 32 + BN / 32;  // vm-ops per wave per stage
  int tid = threadIdx.x;
  int w = tid >> 6, lane = tid & 63;
  int fm = lane & 15, fq = lane >> 4;
  int wm, wn;
  if (BM == 128 && BN == 128) { wm = (w >> 1) * 64; wn = (w & 1) * 64; }
  else if (BM == 128) { wm = w * 32; wn = 0; }
  else { wm = (w >> 1) * 32; wn = (w & 1) * (BN / 2); }
  f32x4 acc[MI][NI] = {};

  auto stage = [&](int kt, int half) {
    bf16_t* Ad = DBUF ? As + half * ASZ : As;
    bf16_t* Bd = DBUF ? Bs + half * BSZ : Bs;
#pragma unroll
    for (int i = 0; i < BM / 32; i++) {  // A: BM rows x 8 chunks
      int c = i * 256 + tid;
      int row = c >> 3, skg = (c & 7) ^ (row & 7);
      async_copy16(A + (size_t)(bm + row) * 1024 + kt + skg * 8, &Ad[c * 8]);
    }
#pragma unroll
    for (int i = 0; i < BN / 32; i++) {  // B: BN rows x 8 chunks
      int c = i * 256 + tid;
      int row = c >> 3, skg = (c & 7) ^ (row & 7);
      async_copy16(Bt + (size_t)(bn + row) * 1024 + kt + skg * 8, &Bd[c * 8]);
    }
  };
  auto compute = [&](int half) {
    const bf16_t* Ac = DBUF ? As + half * ASZ : As;
    const bf16_t* Bc = DBUF ? Bs + half * BSZ : Bs;
#pragma unroll
    for (int ks = 0; ks < 2; ks++) {
      bf16x8 af[MI], bfr[NI];
      int kg = ks * 4 + fq;
#pragma unroll
      for (int mi = 0; mi < MI; mi++) {
        int row = wm + mi * 16 + fm;
        af[mi] = *(const bf16x8*)&Ac[row * 64 + ((kg ^ (row & 7)) * 8)];
      }
#pragma unroll
      for (int ni = 0; ni < NI; ni++) {
        int row = wn + ni * 16 + fm;
        bfr[ni] = *(const bf16x8*)&Bc[row * 64 + ((kg ^ (row & 7)) * 8)];
      }
#pragma unroll
      for (int mi = 0; mi < MI; mi++)
#pragma unroll
        for (int ni = 0; ni < NI; ni++)
          acc[mi][ni] = __builtin_amdgcn_mfma_f32_16x16x32_bf16(
              af[mi], bfr[ni], acc[mi][ni], 0, 0, 0);
    }
  };

  if (DBUF) {
    stage(0, 0);
#pragma unroll
    for (int t = 0; t < 16; t++) {
      if (t < 15) {
        stage((t + 1) * 64, (t + 1) & 1);  // issue next K-tile: stays in flight
        vm_wait<LPS>();                    // own stage(t) loads landed
      } else {
        vm_wait<0>();
      }
      raw_barrier();                // all waves' stage(t) landed
      compute(t & 1);
      asm volatile("s_waitcnt lgkmcnt(0)" ::: "memory");
      raw_barrier();                // buffer (t&1) free for stage(t+2)
    }
  } else {
    for (int kt = 0; kt < 1024; kt += 64) {
      stage(kt, 0);
      __syncthreads();  // drains vmcnt(0): copies visible
      compute(0);
      __syncthreads();  // protect LDS reuse
    }
  }

#pragma unroll
  for (int mi = 0; mi < MI; mi++) {
#pragma unroll
    for (int ni = 0; ni < NI; ni++) {
      int col = bn + wn + ni * 16 + fm;
      float bv = bias[col];
      if (TRANS_OUT) {
        int rowb = bm + wm + mi * 16 + fq * 4;
        bf16x4 w4;
#pragma unroll
        for (int r = 0; r < 4; r++) w4[r] = (bf16_t)(acc[mi][ni][r] + bv);
        *(bf16x4*)&C[(size_t)col * ldC + rowb] = w4;  // C^T: ldC = M
      } else {
#pragma unroll
        for (int r = 0; r < 4; r++) {
          int row = bm + wm + mi * 16 + fq * 4 + r;  // C/D map (m89/m91)
          float v = acc[mi][ni][r] + bv;
          if (HAS_RES) v += (float)res[(size_t)row * ldC + col];
          C[(size_t)row * ldC + col] = (bf16_t)v;
        }
      }
    }
  }
}

// ---------------- mid GEMM: M=4096, N=1024, 64x64 counted-DBUF tiles --------
// 1024 blocks; LDS 32KB -> 5/CU cap (grid gives 4/CU). XCD map: xcd owns a
// contiguous 512-row A-slice (1MB) x all N; A(1MB)+B(2MB) = 3MB fits L2.
template <bool HAS_RES, bool TRANS_OUT>
__global__ __launch_bounds__(256) void gemm_bf16(
    const bf16_t* __restrict__ A, const bf16_t* __restrict__ Bt,
    const float* __restrict__ bias, const bf16_t* __restrict__ res,
    bf16_t* __restrict__ C, int ldC) {
  __shared__ bf16_t As[2 * 64 * 64];  // 16 KB
  __shared__ bf16_t Bs[2 * 64 * 64];  // 16 KB
  int lin = blockIdx.x;
  int xcd = lin & 7, idx = lin >> 3;          // idx in [0,128)
  int ly = idx >> 4, lx = idx & 15;           // 8 x 16
  int bm = (xcd * 8 + ly) * 64;
  int bn = lx * 64;
  gemm_core<64, 64, 2, 2, HAS_RES, TRANS_OUT, true>(A, Bt, bias, res, C, ldC,
                                                    bm, bn, As, Bs);
}

// ======== MEGA-GEMM: all MFMA work that depends only on prep, ONE launch ====
// All segments 64x128 tiles, counted-vmcnt DBUF (48KB LDS -> 3/CU):
//   [0,1536):    qkv C[4096][3072] = xb @ [Wq|Wk|Wv]
//   [1536,1664): Pt[1024][1024]    = wt9 @ w1bf^T
//   [1664,2176): kbuf[4096][1024]  = hb @ Wck
//   [2176,2688): vt[1024][4096]    = (hb @ Wcv)^T
// Segment bases all 0 mod 8 -> per-segment xcd = lin&7 stays valid.
__global__ __launch_bounds__(256) void gemm_mega(
    const bf16_t* __restrict__ xb, const bf16_t* __restrict__ wt0,
    const bf16_t* __restrict__ wt9, const bf16_t* __restrict__ w1bf,
    const bf16_t* __restrict__ hb, const bf16_t* __restrict__ wt4,
    const float* __restrict__ cb, bf16_t* __restrict__ qkv,
    bf16_t* __restrict__ pt, bf16_t* __restrict__ kbuf,
    bf16_t* __restrict__ vt) {
  __shared__ bf16_t As[2 * 64 * 64];   // 16 KB
  __shared__ bf16_t Bs[2 * 128 * 64];  // 32 KB
  int bid = blockIdx.x;
  if (bid < 1536) {           // qkv: 64 bm x 24 bn; XCD: 4 M-groups x 2 N-grps
    int xcd = bid & 7, idx = bid >> 3;        // idx in [0,192)
    int ly = idx / 12, lx = idx - ly * 12;    // 16 x 12
    int bm = ((xcd >> 1) * 16 + ly) * 64;
    int bn = ((xcd & 1) * 12 + lx) * 128;
    gemm_core<64, 128, 2, 4, false, false, true>(xb, wt0, cb, nullptr, qkv,
                                                 3072, bm, bn, As, Bs);
  } else if (bid < 1664) {    // P: 16 bm x 8 bn
    int idx = bid - 1536;
    gemm_core<64, 128, 2, 4, false, false, true>(wt9, w1bf, cb + 6144, nullptr,
                                                 pt, 1024, (idx & 15) * 64,
                                                 (idx >> 4) * 128, As, Bs);
  } else if (bid < 2176) {    // K-proj: xcd owns 512-row slice x all 8 bn
    int idx = bid - 1664;
    int xcd = idx & 7, j = idx >> 3;          // j in [0,64)
    int bm = (xcd * 8 + (j >> 3)) * 64;
    int bn = (j & 7) * 128;
    gemm_core<64, 128, 2, 4, false, false, true>(hb, wt4 + 1048576, cb + 3072,
                                                 nullptr, kbuf, 1024, bm, bn,
                                                 As, Bs);
  } else {                    // V-proj: (hb @ Wcv)^T, ldC = 4096
    int idx = bid - 2176;
    int xcd = idx & 7, j = idx >> 3;
    int bm = (xcd * 8 + (j >> 3)) * 64;
    int bn = (j & 7) * 128;
    gemm_core<64, 128, 2, 4, false, true, true>(hb, wt4 + 2097152, cb + 4096,
                                                nullptr, vt, 4096, bm, bn,
                                                As, Bs);
  }
}

// ---------------- self-attn core: causal softmax over C=64 channels ---------
// ZERO-LDS scalar-path form (R4-verified ~48us = VALU/TRANS issue floor).
__global__ __launch_bounds__(256) void self_attn_kernel(
    const bf16_t* __restrict__ QKV, bf16_t* __restrict__ O) {
  int tid = threadIdx.x;
  int lane = tid & 63;
  int unit = __builtin_amdgcn_readfirstlane(blockIdx.x * 4 + (tid >> 6));
  int m = unit >> 4, h = unit & 15;
  size_t base = (size_t)m * 3072 + h * 64;
  size_t iq = base + lane;
  float qv = (float)QKV[iq];                 // (1/8)*log2e pre-folded
  float kown = (float)QKV[iq + 1024];        // K[lane] (diagonal term)
  float vown = (float)QKV[iq + 2048];        // V[lane]
  const u32x4* Krow = (const u32x4*)(QKV + base + 1024);
  const u32x4* Vrow = (const u32x4*)(QKV + base + 2048);
  u32x4 K4[8], V4[8];
#pragma unroll
  for (int i = 0; i < 8; i++) { K4[i] = Krow[i]; V4[i] = Vrow[i]; }
  float l0 = 0.f, l1 = 0.f, o0 = 0.f, o1 = 0.f;
#pragma unroll
  for (int p = 0; p < 32; p++) {
    unsigned kw = K4[p >> 2][p & 3];   // scalar: (k_{2p}, k_{2p+1}) bf16 pair
    unsigned vw = V4[p >> 2][p & 3];
    float k0 = __uint_as_float(kw << 16);          // SALU
    float k1 = __uint_as_float(kw & 0xffff0000u);  // SALU
    float v0 = __uint_as_float(vw << 16);
    float v1 = __uint_as_float(vw & 0xffff0000u);
    float e0 = fast_exp2(qv * k0);
    float e1 = fast_exp2(qv * k1);
    bool c = lane >= 2 * p + 1;        // ONE cmp; excludes even-lane diagonal
    e0 = c ? e0 : 0.f;
    e1 = c ? e1 : 0.f;
    l0 += e0; o0 = fmaf(e0, v0, o0);
    l1 += e1; o1 = fmaf(e1, v1, o1);
  }
  // even-lane diagonal (k == lane, excluded by the strict shared mask)
  float ed = fast_exp2(qv * kown);
  ed = ((lane & 1) == 0) ? ed : 0.f;
  float l = (l0 + l1) + ed;
  float o = fmaf(ed, vown, o0 + o1);
  O[(size_t)m * 1024 + h * 64 + lane] = (bf16_t)(o * fast_rcp(l));
}

// ---------------- cross-attn, MFMA flash ------------------------------------
__global__ __launch_bounds__(256) void cross_attn_mfma(
    const bf16_t* __restrict__ Q, const bf16_t* __restrict__ Kb,
    const bf16_t* __restrict__ Vt, bf16_t* __restrict__ O) {
  __shared__ bf16_t Ks[64 * 64];
  __shared__ bf16_t Vs[64 * 64];
  int tid = threadIdx.x;
  int w = tid >> 6, lane = tid & 63;
  int fm = lane & 15, fq = lane >> 4;
  int bh = blockIdx.x;
  int b = bh >> 4, h = bh & 15;
  int q0 = blockIdx.y * 64 + w * 16;
  const bf16_t* Qp = Q + (size_t)(b * 512 + q0 + fm) * 1024 + h * 64 + fq * 8;
  bf16x8 qf0 = *(const bf16x8*)Qp;
  bf16x8 qf1 = *(const bf16x8*)(Qp + 32);
  f32x4 o[4] = {};  // O^T tiles ct: lane holds O^T[c=ct*16+fq*4+r][q=fm]
  float mx = -1e30f, l = 0.f;
  for (int k0 = 0; k0 < 512; k0 += 64) {
    __syncthreads();  // previous tile's LDS reads complete
#pragma unroll
    for (int i = 0; i < 2; i++) {  // 64 rows x 8 chunks, XOR swizzle
      int c = i * 256 + tid;
      int row = c >> 3, kg = (c & 7) ^ (row & 7);
      async_copy16(Kb + (size_t)(b * 512 + k0 + row) * 1024 + h * 64 + kg * 8,
                   &Ks[c * 8]);
      async_copy16(Vt + (size_t)(h * 64 + row) * 4096 + b * 512 + k0 + kg * 8,
                   &Vs[c * 8]);
    }
    __syncthreads();  // drain global_load_lds
    // S^T tiles mt: lane holds S^T[k=mt*16+fq*4+r][q=fm]
    f32x4 s[4] = {};
#pragma unroll
    for (int mt = 0; mt < 4; mt++) {
      int row = mt * 16 + fm;
#pragma unroll
      for (int f = 0; f < 2; f++) {
        int kg = f * 4 + fq;
        bf16x8 kf = *(const bf16x8*)&Ks[row * 64 + ((kg ^ (row & 7)) * 8)];
        s[mt] = __builtin_amdgcn_mfma_f32_16x16x32_bf16(
            kf, (f ? qf1 : qf0), s[mt], 0, 0, 0);
      }
    }
    // online softmax (stats per q=fm, replicated across quads)
    float smax = -1e30f;
#pragma unroll
    for (int mt = 0; mt < 4; mt++)
#pragma unroll
      for (int r = 0; r < 4; r++) smax = fmaxf(smax, s[mt][r]);
    smax = fmaxf(smax, __shfl_xor(smax, 16, 64));
    smax = fmaxf(smax, __shfl_xor(smax, 32, 64));
    float nm = fmaxf(mx, smax);
    float corr = __expf(mx - nm);
    float ladd = 0.f;
    unsigned pk0[4], pk1[4];
#pragma unroll
    for (int mt = 0; mt < 4; mt++) {
      float p0 = __expf(s[mt][0] - nm);
      float p1 = __expf(s[mt][1] - nm);
      float p2 = __expf(s[mt][2] - nm);
      float p3 = __expf(s[mt][3] - nm);
      ladd += (p0 + p1) + (p2 + p3);
      pk0[mt] = pack_bf16(p0, p1);
      pk1[mt] = pack_bf16(p2, p3);
    }
    ladd += __shfl_xor(ladd, 16, 64);
    ladd += __shfl_xor(ladd, 32, 64);
    l = l * corr + ladd;
#pragma unroll
    for (int ct = 0; ct < 4; ct++)
#pragma unroll
      for (int r = 0; r < 4; r++) o[ct][r] *= corr;
    union U { unsigned u[4]; bf16x8 v; } pf[2];
    int sl0 = ((fq & 1) * 2) * 16 + fm;
    int sl1 = sl0 + 16;
    bool hi = fq >= 2;
#pragma unroll
    for (int f = 0; f < 2; f++) {
      unsigned a0 = (unsigned)__shfl((int)pk0[f * 2],     sl0, 64);
      unsigned b0 = (unsigned)__shfl((int)pk0[f * 2 + 1], sl0, 64);
      unsigned a1 = (unsigned)__shfl((int)pk1[f * 2],     sl0, 64);
      unsigned b1 = (unsigned)__shfl((int)pk1[f * 2 + 1], sl0, 64);
      unsigned a2 = (unsigned)__shfl((int)pk0[f * 2],     sl1, 64);
      unsigned b2 = (unsigned)__shfl((int)pk0[f * 2 + 1], sl1, 64);
      unsigned a3 = (unsigned)__shfl((int)pk1[f * 2],     sl1, 64);
      unsigned b3 = (unsigned)__shfl((int)pk1[f * 2 + 1], sl1, 64);
      pf[f].u[0] = hi ? b0 : a0;
      pf[f].u[1] = hi ? b1 : a1;
      pf[f].u[2] = hi ? b2 : a2;
      pf[f].u[3] = hi ? b3 : a3;
    }
#pragma unroll
    for (int ct = 0; ct < 4; ct++) {
      int row = ct * 16 + fm;
#pragma unroll
      for (int f = 0; f < 2; f++) {
        int kg = f * 4 + fq;
        bf16x8 vf = *(const bf16x8*)&Vs[row * 64 + ((kg ^ (row & 7)) * 8)];
        o[ct] = __builtin_amdgcn_mfma_f32_16x16x32_bf16(vf, pf[f].v, o[ct], 0, 0, 0);
      }
    }
    mx = nm;
  }
  float inv = 1.f / l;
  bf16_t* Op = O + (size_t)(b * 512 + q0 + fm) * 1024 + h * 64 + fq * 4;
#pragma unroll
  for (int ct = 0; ct < 4; ct++) {
    bf16x4 w4;
    w4[0] = (bf16_t)(o[ct][0] * inv);
    w4[1] = (bf16_t)(o[ct][1] * inv);
    w4[2] = (bf16_t)(o[ct][2] * inv);
    w4[3] = (bf16_t)(o[ct][3] * inv);
    *(bf16x4*)(Op + ct * 16) = w4;
  }
}

// ---------------- LayerNorm D=1024, bf16 in, OutT out -----------------------
template <typename OutT>
__global__ __launch_bounds__(256) void ln_kernel(
    const bf16_t* __restrict__ X, const float* __restrict__ gamma,
    const float* __restrict__ beta, OutT* __restrict__ Y) {
  __shared__ float red[8];
  int row = blockIdx.x;
  int tid = threadIdx.x;
  bf16x4 x4 = *(const bf16x4*)(X + (size_t)row * 1024 + tid * 4);
  float4 v = {(float)x4[0], (float)x4[1], (float)x4[2], (float)x4[3]};
  float s = (v.x + v.y) + (v.z + v.w);
  float ss = fmaf(v.x, v.x, fmaf(v.y, v.y, fmaf(v.z, v.z, v.w * v.w)));
#pragma unroll
  for (int off = 32; off > 0; off >>= 1) {
    s  += __shfl_down(s, off, 64);
    ss += __shfl_down(ss, off, 64);
  }
  if ((tid & 63) == 0) { red[tid >> 6] = s; red[4 + (tid >> 6)] = ss; }
  __syncthreads();
  float S  = (red[0] + red[1]) + (red[2] + red[3]);
  float SS = (red[4] + red[5]) + (red[6] + red[7]);
  float mu = S * (1.f / 1024.f);
  float var = SS * (1.f / 1024.f) - mu * mu;
  float inv = rsqrtf(var + 1e-5f);
  float4 g = *(const float4*)(gamma + tid * 4);
  float4 b = *(const float4*)(beta + tid * 4);
  float r0 = (v.x - mu) * inv * g.x + b.x;
  float r1 = (v.y - mu) * inv * g.y + b.y;
  float r2 = (v.z - mu) * inv * g.z + b.z;
  float r3 = (v.w - mu) * inv * g.w + b.w;
  OutT* yp = Y + (size_t)row * 1024 + tid * 4;
  yp[0] = (OutT)r0; yp[1] = (OutT)r1; yp[2] = (OutT)r2; yp[3] = (OutT)r3;
}

extern "C" void kernel_launch(void* const* d_in, const int* in_sizes, int n_in,
                              void* d_out, int out_size, void* d_ws, size_t ws_size,
                              hipStream_t stream) {
  (void)in_sizes; (void)n_in; (void)out_size; (void)ws_size;
  const float* x  = (const float*)d_in[0];
  const float* hh = (const float*)d_in[1];
  SrcPtrs sp;
  sp.p[0] = (const float*)d_in[2];  sp.p[1] = (const float*)d_in[4];
  sp.p[2] = (const float*)d_in[6];  sp.p[3] = (const float*)d_in[8];
  sp.p[4] = (const float*)d_in[10]; sp.p[5] = (const float*)d_in[12];
  sp.p[6] = (const float*)d_in[14]; sp.p[7] = (const float*)d_in[16];
  sp.p[8] = (const float*)d_in[20]; sp.p[9] = (const float*)d_in[22];
  const float* W1f = (const float*)d_in[20];
  const float* bq  = (const float*)d_in[3];
  const float* bk  = (const float*)d_in[5];
  const float* bv  = (const float*)d_in[7];
  const float* bo  = (const float*)d_in[9];
  const float* bck = (const float*)d_in[13];
  const float* bcv = (const float*)d_in[15];
  const float* bcq = (const float*)d_in[11];
  const float* bco = (const float*)d_in[17];
  const float* gamma = (const float*)d_in[18];
  const float* beta  = (const float*)d_in[19];
  const float* b1  = (const float*)d_in[21];
  const float* b2  = (const float*)d_in[23];
  float* out = (float*)d_out;
  char* ws = (char*)d_ws;
  const size_t MB = 1048576;

  // Workspace lifetime map (max 89 MB):
  //  0..20  wt[0..9]           prep -> end
  // 20..21  cb / cb2           prep_bias -> end
  // 21..29  xb (t1n alias)     prep -> gemm#1(res read); t1n: ln#1 -> gemm#2
  // 29..37  hb (t2n alias)     prep -> mega(A for K/V); t2n: ln#2 -> gemm#3
  // 37..61  qkv                mega -> self_attn (dead after)
  // 37..45  cqbuf              cq-gemm -> cross_attn   (recycles dead qkv)
  // 45..53  g4/f2out           gemm#1/#2/#3 -> ln#1/#2/#3 (recycles dead qkv)
  // 61..69  kbuf               mega(write) -> cross_attn
  // 69..77  vtbuf              mega(write) -> cross_attn
  // 77..85  attn               self_attn -> gemm#1; cross_attn -> gemm#2
  // 85..87  ptbuf              mega -> gemm#3
  // 87..89  w1bf               prep -> mega
  bf16_t* wt[10];
  for (int i = 0; i < 10; i++) wt[i] = (bf16_t*)(ws + (size_t)i * 2 * MB);
  float* cb      = (float*)(ws + 20 * MB);
  float* cb2     = (float*)(ws + 20 * MB + 32768);
  bf16_t* xb     = (bf16_t*)(ws + 21 * MB);
  bf16_t* hb     = (bf16_t*)(ws + 29 * MB);
  bf16_t* qkv    = (bf16_t*)(ws + 37 * MB);
  bf16_t* cqbuf  = (bf16_t*)(ws + 37 * MB);
  bf16_t* g4     = (bf16_t*)(ws + 45 * MB);
  bf16_t* kbuf   = (bf16_t*)(ws + 61 * MB);
  bf16_t* vtbuf  = (bf16_t*)(ws + 69 * MB);
  bf16_t* attn   = (bf16_t*)(ws + 77 * MB);
  bf16_t* ptbuf  = (bf16_t*)(ws + 85 * MB);
  bf16_t* w1bf   = (bf16_t*)(ws + 87 * MB);
  bf16_t* t1n    = xb;
  bf16_t* t2n    = hb;
  bf16_t* f2out  = g4;

  // prep: casts + weight transposes merged (one launch), then biases
  prep_main<<<14848, 256, 0, stream>>>(sp, (bf16_t*)ws, x, hh, W1f, xb, w1bf);
  prep_bias_kernel<<<32, 256, 0, stream>>>(bq, bk, bv, bck, bcv, bcq,
                                           wt[9], b1, b2, cb, cb2);

  // ALL independent MFMA work in one launch: qkv + P + K-proj + V-proj
  gemm_mega<<<2688, 256, 0, stream>>>(xb, wt[0], wt[9], w1bf, hb, wt[4], cb,
                                      qkv, ptbuf, kbuf, vtbuf);
  // self-attn standalone at its VALU/TRANS issue floor (~48us, R4-verified)
  self_attn_kernel<<<16384, 256, 0, stream>>>(qkv, attn);
  gemm_bf16<true, false><<<1024, 256, 0, stream>>>(attn, wt[3], bo, xb, g4, 1024);
  ln_kernel<bf16_t><<<4096, 256, 0, stream>>>(g4, gamma, beta, t1n);
  // cross-attn block: only the cq projection remains serial
  gemm_bf16<false, false><<<1024, 256, 0, stream>>>(t1n, wt[4], cb + 5120,
                                                    nullptr, cqbuf, 1024);
  cross_attn_mfma<<<dim3(128, 8), 256, 0, stream>>>(cqbuf, kbuf, vtbuf, attn);
  gemm_bf16<true, false><<<1024, 256, 0, stream>>>(attn, wt[7], bco, t1n, g4, 1024);
  ln_kernel<bf16_t><<<4096, 256, 0, stream>>>(g4, gamma, beta, t2n);
  // FFN collapsed: out = t2n @ P + (b1@W2 + b2) + t2n
  gemm_bf16<true, false><<<1024, 256, 0, stream>>>(t2n, ptbuf, cb2, t2n, f2out, 1024);
  ln_kernel<float><<<4096, 256, 0, stream>>>(f2out, gamma, beta, out);
}

// Round 11
// 357.380 us; speedup vs baseline: 1.0332x; 1.0261x over previous
//
#include <hip/hip_runtime.h>

typedef __bf16 bf16_t;
typedef bf16_t bf16x8 __attribute__((ext_vector_type(8)));
typedef bf16_t bf16x4 __attribute__((ext_vector_type(4)));
typedef float f32x4 __attribute__((ext_vector_type(4)));
typedef unsigned u32x4 __attribute__((ext_vector_type(4)));

// async global->LDS 16B per lane. LDS dest = wave-uniform base + lane*16
// (m97/m104): per-lane pointers must be linear in lane index.
__device__ __forceinline__ void async_copy16(const void* g, void* l) {
  __builtin_amdgcn_global_load_lds(
      (const __attribute__((address_space(1))) unsigned int*)(unsigned long long)g,
      (__attribute__((address_space(3))) unsigned int*)(unsigned int)(unsigned long long)l,
      16, 0, 0);
}

// counted vmcnt wait (compile-time literal) — T4: never drain to 0 mid-loop
template <int N> __device__ __forceinline__ void vm_wait() {
  if constexpr (N == 0) asm volatile("s_waitcnt vmcnt(0)" ::: "memory");
  else if constexpr (N == 4) asm volatile("s_waitcnt vmcnt(4)" ::: "memory");
  else if constexpr (N == 6) asm volatile("s_waitcnt vmcnt(6)" ::: "memory");
  else if constexpr (N == 8) asm volatile("s_waitcnt vmcnt(8)" ::: "memory");
}
__device__ __forceinline__ void raw_barrier() {
  asm volatile("s_barrier" ::: "memory");
}

// guaranteed single-instruction exp2 / rcp
__device__ __forceinline__ float fast_exp2(float x) {
#if __has_builtin(__builtin_amdgcn_exp2f)
  return __builtin_amdgcn_exp2f(x);
#else
  float r;
  asm volatile("v_exp_f32 %0, %1\n\ts_nop 0" : "=v"(r) : "v"(x));
  return r;
#endif
}
__device__ __forceinline__ float fast_rcp(float x) {
#if __has_builtin(__builtin_amdgcn_rcpf)
  return __builtin_amdgcn_rcpf(x);
#else
  float r;
  asm volatile("v_rcp_f32 %0, %1\n\ts_nop 0" : "=v"(r) : "v"(x));
  return r;
#endif
}

__device__ __forceinline__ unsigned pack_bf16(float x, float y) {
  bf16_t lo = (bf16_t)x, hi = (bf16_t)y;
  unsigned short ul, uh;
  __builtin_memcpy(&ul, &lo, 2);
  __builtin_memcpy(&uh, &hi, 2);
  return (unsigned)ul | ((unsigned)uh << 16);
}

// Q-projection carries 1/8 (softmax scale) * log2e (exp->exp2 conversion)
#define QSCALE 0.180336688f

// ---------------- merged prep: 10 weight transposes + x/h/W1 bf16 cast ------
struct SrcPtrs { const float* p[10]; };
__global__ __launch_bounds__(256) void prep_main(
    SrcPtrs srcs, bf16_t* __restrict__ dstbase,
    const float* __restrict__ a, const float* __restrict__ b,
    const float* __restrict__ w1, bf16_t* __restrict__ dst1,
    bf16_t* __restrict__ dstw) {
  __shared__ float tile[32][33];
  int bid = blockIdx.x;
  int tid = threadIdx.x;
  if (bid < 10240) {
    int z = bid >> 10;
    int rem = bid & 1023;
    const float* src = srcs.p[z];
    bf16_t* dst = dstbase + (size_t)z * 1048576;
    float scale = (z == 0) ? QSCALE : ((z == 4) ? 0.03125f : 1.f);
    int bx = (rem & 31) * 32;   // n base
    int by = (rem >> 5) * 32;   // k base
    int tx = tid & 31, ty = tid >> 5;  // 32x8
#pragma unroll
    for (int i = 0; i < 32; i += 8)
      tile[ty + i][tx] = src[(size_t)(by + ty + i) * 1024 + bx + tx];
    __syncthreads();
#pragma unroll
    for (int i = 0; i < 32; i += 8)
      dst[(size_t)(bx + ty + i) * 1024 + by + tx] = (bf16_t)(tile[tx][ty + i] * scale);
  } else {
    int i = ((bid - 10240) * 256 + tid) * 8;  // [0, 9M)
    const float* s;
    bf16_t* d;
    if (i < 4194304) { s = a + i; d = dst1 + i; }
    else if (i < 8388608) { s = b + i - 4194304; d = dst1 + i; }
    else { s = w1 + i - 8388608; d = dstw + (i - 8388608); }
    float4 u = *(const float4*)s;
    float4 v = *(const float4*)(s + 4);
    bf16x8 o;
    o[0]=(bf16_t)u.x; o[1]=(bf16_t)u.y; o[2]=(bf16_t)u.z; o[3]=(bf16_t)u.w;
    o[4]=(bf16_t)v.x; o[5]=(bf16_t)v.y; o[6]=(bf16_t)v.z; o[7]=(bf16_t)v.w;
    *(bf16x8*)d = o;
  }
}

// --- bias concat [q|k|v|ck|cv|cq|zeros] x1024 + fused FFN bias (blk 28-31) --
__global__ __launch_bounds__(256) void prep_bias_kernel(
    const float* __restrict__ bq, const float* __restrict__ bk,
    const float* __restrict__ bv, const float* __restrict__ bck,
    const float* __restrict__ bcv, const float* __restrict__ bcq,
    const bf16_t* __restrict__ wt9, const float* __restrict__ b1,
    const float* __restrict__ b2, float* __restrict__ cb,
    float* __restrict__ cb2) {
  int bid = blockIdx.x;
  if (bid < 28) {
    int i = bid * 256 + threadIdx.x;
    if (i < 1024) cb[i] = bq[i] * QSCALE;
    else if (i < 2048) cb[i] = bk[i - 1024];
    else if (i < 3072) cb[i] = bv[i - 2048];
    else if (i < 4096) cb[i] = bck[i - 3072];
    else if (i < 5120) cb[i] = bcv[i - 4096];
    else if (i < 6144) cb[i] = bcq[i - 5120] * 0.03125f;
    else cb[i] = 0.f;  // zeros for the P-GEMM bias
  } else {
    // cb2[n] = sum_h b1[h]*W2[h][n] + b2[n];  wt9[n][h] = W2[h][n]
    int n = (bid - 28) * 256 + threadIdx.x;
    const bf16_t* row = wt9 + (size_t)n * 1024;
    float acc = 0.f;
#pragma unroll 4
    for (int h = 0; h < 1024; h += 8) {
      bf16x8 v = *(const bf16x8*)(row + h);
      float4 ba = *(const float4*)(b1 + h);
      float4 bb = *(const float4*)(b1 + h + 4);
      acc += ba.x*(float)v[0] + ba.y*(float)v[1] + ba.z*(float)v[2] + ba.w*(float)v[3]
           + bb.x*(float)v[4] + bb.y*(float)v[5] + bb.z*(float)v[6] + bb.w*(float)v[7];
    }
    cb2[n] = acc + b2[n];
  }
}

// ---------------- shared GEMM core: C[*,ldC] = A[*,1024] @ Bt[*,1024]^T -----
// DBUF=true: counted-vmcnt 2-phase (T3+T4 minimum, R10-validated). Per step:
//   stage(t+1) -> s_waitcnt vmcnt(LPS) -> s_barrier -> compute(t)
//   -> lgkmcnt(0) -> s_barrier.
template <int BM, int BN, int MI, int NI, bool HAS_RES, bool TRANS_OUT, bool DBUF>
__device__ __forceinline__ void gemm_core(
    const bf16_t* __restrict__ A, const bf16_t* __restrict__ Bt,
    const float* __restrict__ bias, const bf16_t* __restrict__ res,
    bf16_t* __restrict__ C, int ldC, int bm, int bn,
    bf16_t* As, bf16_t* Bs) {
  constexpr int ASZ = BM * 64, BSZ = BN * 64;
  constexpr int LPS = BM / 32 + BN / 32;  // vm-ops per wave per stage
  int tid = threadIdx.x;
  int w = tid >> 6, lane = tid & 63;
  int fm = lane & 15, fq = lane >> 4;
  int wm, wn;
  if (BM == 128 && BN == 128) { wm = (w >> 1) * 64; wn = (w & 1) * 64; }
  else if (BM == 128) { wm = w * 32; wn = 0; }
  else { wm = (w >> 1) * 32; wn = (w & 1) * (BN / 2); }
  f32x4 acc[MI][NI] = {};

  auto stage = [&](int kt, int half) {
    bf16_t* Ad = DBUF ? As + half * ASZ : As;
    bf16_t* Bd = DBUF ? Bs + half * BSZ : Bs;
#pragma unroll
    for (int i = 0; i < BM / 32; i++) {  // A: BM rows x 8 chunks
      int c = i * 256 + tid;
      int row = c >> 3, skg = (c & 7) ^ (row & 7);
      async_copy16(A + (size_t)(bm + row) * 1024 + kt + skg * 8, &Ad[c * 8]);
    }
#pragma unroll
    for (int i = 0; i < BN / 32; i++) {  // B: BN rows x 8 chunks
      int c = i * 256 + tid;
      int row = c >> 3, skg = (c & 7) ^ (row & 7);
      async_copy16(Bt + (size_t)(bn + row) * 1024 + kt + skg * 8, &Bd[c * 8]);
    }
  };
  auto compute = [&](int half) {
    const bf16_t* Ac = DBUF ? As + half * ASZ : As;
    const bf16_t* Bc = DBUF ? Bs + half * BSZ : Bs;
#pragma unroll
    for (int ks = 0; ks < 2; ks++) {
      bf16x8 af[MI], bfr[NI];
      int kg = ks * 4 + fq;
#pragma unroll
      for (int mi = 0; mi < MI; mi++) {
        int row = wm + mi * 16 + fm;
        af[mi] = *(const bf16x8*)&Ac[row * 64 + ((kg ^ (row & 7)) * 8)];
      }
#pragma unroll
      for (int ni = 0; ni < NI; ni++) {
        int row = wn + ni * 16 + fm;
        bfr[ni] = *(const bf16x8*)&Bc[row * 64 + ((kg ^ (row & 7)) * 8)];
      }
#pragma unroll
      for (int mi = 0; mi < MI; mi++)
#pragma unroll
        for (int ni = 0; ni < NI; ni++)
          acc[mi][ni] = __builtin_amdgcn_mfma_f32_16x16x32_bf16(
              af[mi], bfr[ni], acc[mi][ni], 0, 0, 0);
    }
  };

  if (DBUF) {
    stage(0, 0);
#pragma unroll
    for (int t = 0; t < 16; t++) {
      if (t < 15) {
        stage((t + 1) * 64, (t + 1) & 1);  // issue next K-tile: stays in flight
        vm_wait<LPS>();                    // own stage(t) loads landed
      } else {
        vm_wait<0>();
      }
      raw_barrier();                // all waves' stage(t) landed
      compute(t & 1);
      asm volatile("s_waitcnt lgkmcnt(0)" ::: "memory");
      raw_barrier();                // buffer (t&1) free for stage(t+2)
    }
  } else {
    for (int kt = 0; kt < 1024; kt += 64) {
      stage(kt, 0);
      __syncthreads();  // drains vmcnt(0): copies visible
      compute(0);
      __syncthreads();  // protect LDS reuse
    }
  }

#pragma unroll
  for (int mi = 0; mi < MI; mi++) {
#pragma unroll
    for (int ni = 0; ni < NI; ni++) {
      int col = bn + wn + ni * 16 + fm;
      float bv = bias[col];
      if (TRANS_OUT) {
        int rowb = bm + wm + mi * 16 + fq * 4;
        bf16x4 w4;
#pragma unroll
        for (int r = 0; r < 4; r++) w4[r] = (bf16_t)(acc[mi][ni][r] + bv);
        *(bf16x4*)&C[(size_t)col * ldC + rowb] = w4;  // C^T: ldC = M
      } else {
#pragma unroll
        for (int r = 0; r < 4; r++) {
          int row = bm + wm + mi * 16 + fq * 4 + r;  // C/D map (m89/m91)
          float v = acc[mi][ni][r] + bv;
          if (HAS_RES) v += (float)res[(size_t)row * ldC + col];
          C[(size_t)row * ldC + col] = (bf16_t)v;
        }
      }
    }
  }
}

// ---------------- mid GEMM: M=4096, N=1024, 64x64 counted-DBUF tiles --------
template <bool HAS_RES, bool TRANS_OUT>
__global__ __launch_bounds__(256) void gemm_bf16(
    const bf16_t* __restrict__ A, const bf16_t* __restrict__ Bt,
    const float* __restrict__ bias, const bf16_t* __restrict__ res,
    bf16_t* __restrict__ C, int ldC) {
  __shared__ bf16_t As[2 * 64 * 64];  // 16 KB
  __shared__ bf16_t Bs[2 * 64 * 64];  // 16 KB
  int lin = blockIdx.x;
  int xcd = lin & 7, idx = lin >> 3;          // idx in [0,128)
  int ly = idx >> 4, lx = idx & 15;           // 8 x 16
  int bm = (xcd * 8 + ly) * 64;
  int bn = lx * 64;
  gemm_core<64, 64, 2, 2, HAS_RES, TRANS_OUT, true>(A, Bt, bias, res, C, ldC,
                                                    bm, bn, As, Bs);
}

// ======== MEGA-GEMM: all MFMA work that depends only on prep, ONE launch ====
// 64x128 tiles, counted-vmcnt DBUF (48KB LDS). At 768 TF this structure is
// ~85% of the m97 2-phase ceiling for these shapes (LDS-write-BW capped:
// FLOP/LDS-byte = 43 vs ~102 needed) — considered done.
__global__ __launch_bounds__(256) void gemm_mega(
    const bf16_t* __restrict__ xb, const bf16_t* __restrict__ wt0,
    const bf16_t* __restrict__ wt9, const bf16_t* __restrict__ w1bf,
    const bf16_t* __restrict__ hb, const bf16_t* __restrict__ wt4,
    const float* __restrict__ cb, bf16_t* __restrict__ qkv,
    bf16_t* __restrict__ pt, bf16_t* __restrict__ kbuf,
    bf16_t* __restrict__ vt) {
  __shared__ bf16_t As[2 * 64 * 64];   // 16 KB
  __shared__ bf16_t Bs[2 * 128 * 64];  // 32 KB
  int bid = blockIdx.x;
  if (bid < 1536) {           // qkv: 64 bm x 24 bn; XCD: 4 M-groups x 2 N-grps
    int xcd = bid & 7, idx = bid >> 3;        // idx in [0,192)
    int ly = idx / 12, lx = idx - ly * 12;    // 16 x 12
    int bm = ((xcd >> 1) * 16 + ly) * 64;
    int bn = ((xcd & 1) * 12 + lx) * 128;
    gemm_core<64, 128, 2, 4, false, false, true>(xb, wt0, cb, nullptr, qkv,
                                                 3072, bm, bn, As, Bs);
  } else if (bid < 1664) {    // P: 16 bm x 8 bn
    int idx = bid - 1536;
    gemm_core<64, 128, 2, 4, false, false, true>(wt9, w1bf, cb + 6144, nullptr,
                                                 pt, 1024, (idx & 15) * 64,
                                                 (idx >> 4) * 128, As, Bs);
  } else if (bid < 2176) {    // K-proj: xcd owns 512-row slice x all 8 bn
    int idx = bid - 1664;
    int xcd = idx & 7, j = idx >> 3;          // j in [0,64)
    int bm = (xcd * 8 + (j >> 3)) * 64;
    int bn = (j & 7) * 128;
    gemm_core<64, 128, 2, 4, false, false, true>(hb, wt4 + 1048576, cb + 3072,
                                                 nullptr, kbuf, 1024, bm, bn,
                                                 As, Bs);
  } else {                    // V-proj: (hb @ Wcv)^T, ldC = 4096
    int idx = bid - 2176;
    int xcd = idx & 7, j = idx >> 3;
    int bm = (xcd * 8 + (j >> 3)) * 64;
    int bn = (j & 7) * 128;
    gemm_core<64, 128, 2, 4, false, true, true>(hb, wt4 + 2097152, cb + 4096,
                                                nullptr, vt, 4096, bm, bn,
                                                As, Bs);
  }
}

// ---------------- self-attn core: causal softmax over C=64 channels ---------
// ZERO-LDS scalar-path form (R4). VALUBusy ~90% => issue-bound; R11 cuts
// VALU/pair 9 -> 6 by folding the causal mask into the exp2 argument:
// precompute B[p] = (lane >= 2p+1) ? 0 : -512 once (32 VGPRs, unrolled
// static-index), then arg = fma(q, k, B[p]); exp2(-512+eps) == +0 exactly
// (|q*k| << 512), so masked terms contribute exactly 0 — bit-equivalent to
// the cndmask version. Even-lane diagonal fixup unchanged.
__global__ __launch_bounds__(256) void self_attn_kernel(
    const bf16_t* __restrict__ QKV, bf16_t* __restrict__ O) {
  int tid = threadIdx.x;
  int lane = tid & 63;
  int unit = __builtin_amdgcn_readfirstlane(blockIdx.x * 4 + (tid >> 6));
  int m = unit >> 4, h = unit & 15;
  size_t base = (size_t)m * 3072 + h * 64;
  size_t iq = base + lane;
  float qv = (float)QKV[iq];                 // (1/8)*log2e pre-folded
  float kown = (float)QKV[iq + 1024];        // K[lane] (diagonal term)
  float vown = (float)QKV[iq + 2048];        // V[lane]
  const u32x4* Krow = (const u32x4*)(QKV + base + 1024);
  const u32x4* Vrow = (const u32x4*)(QKV + base + 2048);
  u32x4 K4[8], V4[8];
#pragma unroll
  for (int i = 0; i < 8; i++) { K4[i] = Krow[i]; V4[i] = Vrow[i]; }
  // mask-bias table: one register per pair, compile-time indexed
  float B[32];
#pragma unroll
  for (int p = 0; p < 32; p++) B[p] = (lane >= 2 * p + 1) ? 0.f : -512.f;
  float l0 = 0.f, l1 = 0.f, o0 = 0.f, o1 = 0.f;
#pragma unroll
  for (int p = 0; p < 32; p++) {
    unsigned kw = K4[p >> 2][p & 3];   // scalar: (k_{2p}, k_{2p+1}) bf16 pair
    unsigned vw = V4[p >> 2][p & 3];
    float k0 = __uint_as_float(kw << 16);          // SALU
    float k1 = __uint_as_float(kw & 0xffff0000u);  // SALU
    float v0 = __uint_as_float(vw << 16);
    float v1 = __uint_as_float(vw & 0xffff0000u);
    float e0 = fast_exp2(fmaf(qv, k0, B[p]));  // mask folded into arg
    float e1 = fast_exp2(fmaf(qv, k1, B[p]));
    l0 += e0; o0 = fmaf(e0, v0, o0);
    l1 += e1; o1 = fmaf(e1, v1, o1);
  }
  // even-lane diagonal (k == lane, excluded by the strict shared mask)
  float ed = fast_exp2(qv * kown);
  ed = ((lane & 1) == 0) ? ed : 0.f;
  float l = (l0 + l1) + ed;
  float o = fmaf(ed, vown, o0 + o1);
  O[(size_t)m * 1024 + h * 64 + lane] = (bf16_t)(o * fast_rcp(l));
}

// ---------------- cross-attn, MFMA flash ------------------------------------
// R11: counted-vmcnt double-buffered K/V staging (same discipline as
// gemm_core, validated R10). Per tile: stage(t+1) [4 vm-ops] -> vmcnt(4)
// -> barrier -> QK/softmax/PV on buf t&1 -> lgkmcnt(0) -> barrier.
// LDS 16->32KB (cap 5/CU, grid gives 4/CU).
__global__ __launch_bounds__(256) void cross_attn_mfma(
    const bf16_t* __restrict__ Q, const bf16_t* __restrict__ Kb,
    const bf16_t* __restrict__ Vt, bf16_t* __restrict__ O) {
  __shared__ bf16_t Ks[2 * 64 * 64];
  __shared__ bf16_t Vs[2 * 64 * 64];
  int tid = threadIdx.x;
  int w = tid >> 6, lane = tid & 63;
  int fm = lane & 15, fq = lane >> 4;
  int bh = blockIdx.x;
  int b = bh >> 4, h = bh & 15;
  int q0 = blockIdx.y * 64 + w * 16;
  const bf16_t* Qp = Q + (size_t)(b * 512 + q0 + fm) * 1024 + h * 64 + fq * 8;
  bf16x8 qf0 = *(const bf16x8*)Qp;
  bf16x8 qf1 = *(const bf16x8*)(Qp + 32);
  f32x4 o[4] = {};  // O^T tiles ct: lane holds O^T[c=ct*16+fq*4+r][q=fm]
  float mx = -1e30f, l = 0.f;

  auto stage_kv = [&](int k0, int half) {
#pragma unroll
    for (int i = 0; i < 2; i++) {  // 64 rows x 8 chunks, XOR swizzle
      int c = i * 256 + tid;
      int row = c >> 3, kg = (c & 7) ^ (row & 7);
      async_copy16(Kb + (size_t)(b * 512 + k0 + row) * 1024 + h * 64 + kg * 8,
                   &Ks[half * 4096 + c * 8]);
      async_copy16(Vt + (size_t)(h * 64 + row) * 4096 + b * 512 + k0 + kg * 8,
                   &Vs[half * 4096 + c * 8]);
    }
  };

  stage_kv(0, 0);
  for (int t = 0; t < 8; t++) {
    if (t < 7) {
      stage_kv((t + 1) * 64, (t + 1) & 1);  // next tile in flight
      vm_wait<4>();                         // own stage(t) landed
    } else {
      vm_wait<0>();
    }
    raw_barrier();                          // all waves' stage(t) landed
    const bf16_t* Kc = Ks + (t & 1) * 4096;
    const bf16_t* Vc = Vs + (t & 1) * 4096;
    // S^T tiles mt: lane holds S^T[k=mt*16+fq*4+r][q=fm]
    f32x4 s[4] = {};
#pragma unroll
    for (int mt = 0; mt < 4; mt++) {
      int row = mt * 16 + fm;
#pragma unroll
      for (int f = 0; f < 2; f++) {
        int kg = f * 4 + fq;
        bf16x8 kf = *(const bf16x8*)&Kc[row * 64 + ((kg ^ (row & 7)) * 8)];
        s[mt] = __builtin_amdgcn_mfma_f32_16x16x32_bf16(
            kf, (f ? qf1 : qf0), s[mt], 0, 0, 0);
      }
    }
    // online softmax (stats per q=fm, replicated across quads)
    float smax = -1e30f;
#pragma unroll
    for (int mt = 0; mt < 4; mt++)
#pragma unroll
      for (int r = 0; r < 4; r++) smax = fmaxf(smax, s[mt][r]);
    smax = fmaxf(smax, __shfl_xor(smax, 16, 64));
    smax = fmaxf(smax, __shfl_xor(smax, 32, 64));
    float nm = fmaxf(mx, smax);
    float corr = __expf(mx - nm);
    float ladd = 0.f;
    unsigned pk0[4], pk1[4];
#pragma unroll
    for (int mt = 0; mt < 4; mt++) {
      float p0 = __expf(s[mt][0] - nm);
      float p1 = __expf(s[mt][1] - nm);
      float p2 = __expf(s[mt][2] - nm);
      float p3 = __expf(s[mt][3] - nm);
      ladd += (p0 + p1) + (p2 + p3);
      pk0[mt] = pack_bf16(p0, p1);
      pk1[mt] = pack_bf16(p2, p3);
    }
    ladd += __shfl_xor(ladd, 16, 64);
    ladd += __shfl_xor(ladd, 32, 64);
    l = l * corr + ladd;
#pragma unroll
    for (int ct = 0; ct < 4; ct++)
#pragma unroll
      for (int r = 0; r < 4; r++) o[ct][r] *= corr;
    union U { unsigned u[4]; bf16x8 v; } pf[2];
    int sl0 = ((fq & 1) * 2) * 16 + fm;
    int sl1 = sl0 + 16;
    bool hi = fq >= 2;
#pragma unroll
    for (int f = 0; f < 2; f++) {
      unsigned a0 = (unsigned)__shfl((int)pk0[f * 2],     sl0, 64);
      unsigned b0 = (unsigned)__shfl((int)pk0[f * 2 + 1], sl0, 64);
      unsigned a1 = (unsigned)__shfl((int)pk1[f * 2],     sl0, 64);
      unsigned b1 = (unsigned)__shfl((int)pk1[f * 2 + 1], sl0, 64);
      unsigned a2 = (unsigned)__shfl((int)pk0[f * 2],     sl1, 64);
      unsigned b2 = (unsigned)__shfl((int)pk0[f * 2 + 1], sl1, 64);
      unsigned a3 = (unsigned)__shfl((int)pk1[f * 2],     sl1, 64);
      unsigned b3 = (unsigned)__shfl((int)pk1[f * 2 + 1], sl1, 64);
      pf[f].u[0] = hi ? b0 : a0;
      pf[f].u[1] = hi ? b1 : a1;
      pf[f].u[2] = hi ? b2 : a2;
      pf[f].u[3] = hi ? b3 : a3;
    }
#pragma unroll
    for (int ct = 0; ct < 4; ct++) {
      int row = ct * 16 + fm;
#pragma unroll
      for (int f = 0; f < 2; f++) {
        int kg = f * 4 + fq;
        bf16x8 vf = *(const bf16x8*)&Vc[row * 64 + ((kg ^ (row & 7)) * 8)];
        o[ct] = __builtin_amdgcn_mfma_f32_16x16x32_bf16(vf, pf[f].v, o[ct], 0, 0, 0);
      }
    }
    mx = nm;
    asm volatile("s_waitcnt lgkmcnt(0)" ::: "memory");
    raw_barrier();  // buffer (t&1) free for stage(t+2)
  }
  float inv = 1.f / l;
  bf16_t* Op = O + (size_t)(b * 512 + q0 + fm) * 1024 + h * 64 + fq * 4;
#pragma unroll
  for (int ct = 0; ct < 4; ct++) {
    bf16x4 w4;
    w4[0] = (bf16_t)(o[ct][0] * inv);
    w4[1] = (bf16_t)(o[ct][1] * inv);
    w4[2] = (bf16_t)(o[ct][2] * inv);
    w4[3] = (bf16_t)(o[ct][3] * inv);
    *(bf16x4*)(Op + ct * 16) = w4;
  }
}

// ---------------- LayerNorm D=1024, bf16 in, OutT out -----------------------
template <typename OutT>
__global__ __launch_bounds__(256) void ln_kernel(
    const bf16_t* __restrict__ X, const float* __restrict__ gamma,
    const float* __restrict__ beta, OutT* __restrict__ Y) {
  __shared__ float red[8];
  int row = blockIdx.x;
  int tid = threadIdx.x;
  bf16x4 x4 = *(const bf16x4*)(X + (size_t)row * 1024 + tid * 4);
  float4 v = {(float)x4[0], (float)x4[1], (float)x4[2], (float)x4[3]};
  float s = (v.x + v.y) + (v.z + v.w);
  float ss = fmaf(v.x, v.x, fmaf(v.y, v.y, fmaf(v.z, v.z, v.w * v.w)));
#pragma unroll
  for (int off = 32; off > 0; off >>= 1) {
    s  += __shfl_down(s, off, 64);
    ss += __shfl_down(ss, off, 64);
  }
  if ((tid & 63) == 0) { red[tid >> 6] = s; red[4 + (tid >> 6)] = ss; }
  __syncthreads();
  float S  = (red[0] + red[1]) + (red[2] + red[3]);
  float SS = (red[4] + red[5]) + (red[6] + red[7]);
  float mu = S * (1.f / 1024.f);
  float var = SS * (1.f / 1024.f) - mu * mu;
  float inv = rsqrtf(var + 1e-5f);
  float4 g = *(const float4*)(gamma + tid * 4);
  float4 b = *(const float4*)(beta + tid * 4);
  float r0 = (v.x - mu) * inv * g.x + b.x;
  float r1 = (v.y - mu) * inv * g.y + b.y;
  float r2 = (v.z - mu) * inv * g.z + b.z;
  float r3 = (v.w - mu) * inv * g.w + b.w;
  OutT* yp = Y + (size_t)row * 1024 + tid * 4;
  yp[0] = (OutT)r0; yp[1] = (OutT)r1; yp[2] = (OutT)r2; yp[3] = (OutT)r3;
}

extern "C" void kernel_launch(void* const* d_in, const int* in_sizes, int n_in,
                              void* d_out, int out_size, void* d_ws, size_t ws_size,
                              hipStream_t stream) {
  (void)in_sizes; (void)n_in; (void)out_size; (void)ws_size;
  const float* x  = (const float*)d_in[0];
  const float* hh = (const float*)d_in[1];
  SrcPtrs sp;
  sp.p[0] = (const float*)d_in[2];  sp.p[1] = (const float*)d_in[4];
  sp.p[2] = (const float*)d_in[6];  sp.p[3] = (const float*)d_in[8];
  sp.p[4] = (const float*)d_in[10]; sp.p[5] = (const float*)d_in[12];
  sp.p[6] = (const float*)d_in[14]; sp.p[7] = (const float*)d_in[16];
  sp.p[8] = (const float*)d_in[20]; sp.p[9] = (const float*)d_in[22];
  const float* W1f = (const float*)d_in[20];
  const float* bq  = (const float*)d_in[3];
  const float* bk  = (const float*)d_in[5];
  const float* bv  = (const float*)d_in[7];
  const float* bo  = (const float*)d_in[9];
  const float* bck = (const float*)d_in[13];
  const float* bcv = (const float*)d_in[15];
  const float* bcq = (const float*)d_in[11];
  const float* bco = (const float*)d_in[17];
  const float* gamma = (const float*)d_in[18];
  const float* beta  = (const float*)d_in[19];
  const float* b1  = (const float*)d_in[21];
  const float* b2  = (const float*)d_in[23];
  float* out = (float*)d_out;
  char* ws = (char*)d_ws;
  const size_t MB = 1048576;

  // Workspace lifetime map (max 89 MB):
  //  0..20  wt[0..9]           prep -> end
  // 20..21  cb / cb2           prep_bias -> end
  // 21..29  xb (t1n alias)     prep -> gemm#1(res read); t1n: ln#1 -> gemm#2
  // 29..37  hb (t2n alias)     prep -> mega(A for K/V); t2n: ln#2 -> gemm#3
  // 37..61  qkv                mega -> self_attn (dead after)
  // 37..45  cqbuf              cq-gemm -> cross_attn   (recycles dead qkv)
  // 45..53  g4/f2out           gemm#1/#2/#3 -> ln#1/#2/#3 (recycles dead qkv)
  // 61..69  kbuf               mega(write) -> cross_attn
  // 69..77  vtbuf              mega(write) -> cross_attn
  // 77..85  attn               self_attn -> gemm#1; cross_attn -> gemm#2
  // 85..87  ptbuf              mega -> gemm#3
  // 87..89  w1bf               prep -> mega
  bf16_t* wt[10];
  for (int i = 0; i < 10; i++) wt[i] = (bf16_t*)(ws + (size_t)i * 2 * MB);
  float* cb      = (float*)(ws + 20 * MB);
  float* cb2     = (float*)(ws + 20 * MB + 32768);
  bf16_t* xb     = (bf16_t*)(ws + 21 * MB);
  bf16_t* hb     = (bf16_t*)(ws + 29 * MB);
  bf16_t* qkv    = (bf16_t*)(ws + 37 * MB);
  bf16_t* cqbuf  = (bf16_t*)(ws + 37 * MB);
  bf16_t* g4     = (bf16_t*)(ws + 45 * MB);
  bf16_t* kbuf   = (bf16_t*)(ws + 61 * MB);
  bf16_t* vtbuf  = (bf16_t*)(ws + 69 * MB);
  bf16_t* attn   = (bf16_t*)(ws + 77 * MB);
  bf16_t* ptbuf  = (bf16_t*)(ws + 85 * MB);
  bf16_t* w1bf   = (bf16_t*)(ws + 87 * MB);
  bf16_t* t1n    = xb;
  bf16_t* t2n    = hb;
  bf16_t* f2out  = g4;

  // prep: casts + weight transposes merged (one launch), then biases
  prep_main<<<14848, 256, 0, stream>>>(sp, (bf16_t*)ws, x, hh, W1f, xb, w1bf);
  prep_bias_kernel<<<32, 256, 0, stream>>>(bq, bk, bv, bck, bcv, bcq,
                                           wt[9], b1, b2, cb, cb2);

  // ALL independent MFMA work in one launch: qkv + P + K-proj + V-proj
  gemm_mega<<<2688, 256, 0, stream>>>(xb, wt[0], wt[9], w1bf, hb, wt[4], cb,
                                      qkv, ptbuf, kbuf, vtbuf);
  // self-attn standalone (mask folded into exp2 arg; VALU/pair 9 -> 6)
  self_attn_kernel<<<16384, 256, 0, stream>>>(qkv, attn);
  gemm_bf16<true, false><<<1024, 256, 0, stream>>>(attn, wt[3], bo, xb, g4, 1024);
  ln_kernel<bf16_t><<<4096, 256, 0, stream>>>(g4, gamma, beta, t1n);
  // cross-attn block: only the cq projection remains serial
  gemm_bf16<false, false><<<1024, 256, 0, stream>>>(t1n, wt[4], cb + 5120,
                                                    nullptr, cqbuf, 1024);
  cross_attn_mfma<<<dim3(128, 8), 256, 0, stream>>>(cqbuf, kbuf, vtbuf, attn);
  gemm_bf16<true, false><<<1024, 256, 0, stream>>>(attn, wt[7], bco, t1n, g4, 1024);
  ln_kernel<bf16_t><<<4096, 256, 0, stream>>>(g4, gamma, beta, t2n);
  // FFN collapsed: out = t2n @ P + (b1@W2 + b2) + t2n
  gemm_bf16<true, false><<<1024, 256, 0, stream>>>(t2n, ptbuf, cb2, t2n, f2out, 1024);
  ln_kernel<float><<<4096, 256, 0, stream>>>(f2out, gamma, beta, out);
}